// Round 7
// baseline (474.830 us; speedup 1.0000x reference)
//
#include <hip/hip_runtime.h>
#include <stdint.h>

// ---------------- types ----------------
typedef short   bf16x8 __attribute__((ext_vector_type(8)));
typedef float   f32x4  __attribute__((ext_vector_type(4)));
typedef float   f32x16 __attribute__((ext_vector_type(16)));
typedef int     i32x4  __attribute__((ext_vector_type(4)));
typedef int     i32x8  __attribute__((ext_vector_type(8)));
typedef unsigned short u16x8 __attribute__((ext_vector_type(8)));
typedef unsigned long long u64;
typedef long long i64;
typedef long long i64x2 __attribute__((ext_vector_type(2)));

#define B_ROWS 4096
#define D_IN   1024
#define L_DIM  16384
#define NBIN   2048
#define CCAP   1024
#define SLOTS  32
#define W8SCALE 1200.0f

// ---------------- helpers ----------------
__device__ __forceinline__ unsigned short f2bf(float f) {
  unsigned int u = __float_as_uint(f);
  u = (u + 0x7FFFu + ((u >> 16) & 1u)) >> 16;   // RNE to bf16
  return (unsigned short)u;
}
__device__ __forceinline__ float bf2f(unsigned short h) {
  return __uint_as_float(((unsigned int)h) << 16);
}
// f32 -> OCP e4m3fn (RNE, flush exp<=0 to 0, clamp 448)
__device__ __forceinline__ unsigned char f2e4m3(float v) {
  unsigned int u = __float_as_uint(v);
  unsigned int s = (u >> 24) & 0x80u;
  unsigned int a = u & 0x7FFFFFFFu;
  unsigned int r = (a + 0x0007FFFFu + ((a >> 20) & 1u)) >> 20;   // (exp<<3)|man, rounded
  if (r <= (120u << 3)) return (unsigned char)s;                 // underflow -> +-0
  r -= (120u << 3);
  if (r > 0x7Eu) r = 0x7Eu;                                      // clamp to 448
  return (unsigned char)(s | r);
}
__device__ __forceinline__ float e4m3f(unsigned char b) {
  unsigned int e = (b >> 3) & 0xFu, m = b & 7u, s = ((unsigned int)b & 0x80u) << 24;
  if (e == 0) return __uint_as_float(s);
  return __uint_as_float(s | ((e + 120u) << 23) | (m << 20));
}
__device__ __forceinline__ unsigned int sortkey(float f) {
  unsigned int u = __float_as_uint(f);
  return (u & 0x80000000u) ? ~u : (u | 0x80000000u);
}
__device__ __forceinline__ float keyval(unsigned int k) {
  unsigned int u = (k & 0x80000000u) ? (k & 0x7FFFFFFFu) : ~k;
  return __uint_as_float(u);
}
__device__ __forceinline__ int binof(float v) {
  int b = (int)((v + 2.0f) * (2048.0f / 7.0f));
  return b < 0 ? 0 : (b > 2047 ? 2047 : b);
}
__device__ __forceinline__ void gl_lds16(const void* g, void* l) {
  __builtin_amdgcn_global_load_lds(
      (const __attribute__((address_space(1))) unsigned int*)g,
      (__attribute__((address_space(3))) unsigned int*)l, 16, 0, 0);
}
__device__ __forceinline__ float waveSum(float v) {
  #pragma unroll
  for (int m = 32; m; m >>= 1) v += __shfl_xor(v, m);
  return v;
}

// ---------------- k0: zero scalars + column partials + row counters ----------------
__global__ void k_zero(float* scal, float* colsum, float* colsq, unsigned int* rowcnt) {
  int t = blockIdx.x * blockDim.x + threadIdx.x;
  if (t < 8) scal[t] = 0.f;              // [0]=loss, [1]=var
  if (t < 1024) { colsum[t] = 0.f; colsq[t] = 0.f; }
  for (int i = t; i < B_ROWS; i += gridDim.x * blockDim.x) rowcnt[i] = 0u;
}

// ---------------- convert f32 -> bf16 (vectorized) ----------------
__global__ void k_convert(const float* __restrict__ in, unsigned short* __restrict__ out, int n4) {
  int i = blockIdx.x * blockDim.x + threadIdx.x;
  int stride = gridDim.x * blockDim.x;
  for (; i < n4; i += stride) {
    f32x4 v = *((const f32x4*)in + i);
    ushort4 o;
    o.x = f2bf(v[0]); o.y = f2bf(v[1]); o.z = f2bf(v[2]); o.w = f2bf(v[3]);
    *((ushort4*)out + i) = o;
  }
}

// ---------------- convert f32 -> fp8 e4m3, IDENTITY layout ----------------
// The 32x32x64 f8f6f4 fragment is 32 contiguous K-bytes per lane, so no permutation.
__global__ void k_convert_fp8(const float* __restrict__ in, unsigned char* __restrict__ out, int n4) {
  int i = blockIdx.x * blockDim.x + threadIdx.x;
  int stride = gridDim.x * blockDim.x;
  for (; i < n4; i += stride) {
    f32x4 v = *((const f32x4*)in + i);
    unsigned int u = 0;
    #pragma unroll
    for (int j = 0; j < 4; j++) u |= ((unsigned int)f2e4m3(v[j])) << (8 * j);
    *((unsigned int*)out + i) = u;
  }
}

// ---------------- convert f32 -> int8 (scale W8SCALE, clamp +-127), packed 4/word ----------------
__global__ void k_convert_i8(const float* __restrict__ in, unsigned int* __restrict__ out, int n4) {
  int i = blockIdx.x * blockDim.x + threadIdx.x;
  int stride = gridDim.x * blockDim.x;
  for (; i < n4; i += stride) {
    f32x4 v = *((const f32x4*)in + i);
    unsigned int u = 0;
    #pragma unroll
    for (int j = 0; j < 4; j++) {
      int q = (int)rintf(v[j] * W8SCALE);
      q = q > 127 ? 127 : (q < -127 ? -127 : q);
      u |= ((unsigned int)q & 0xFFu) << (8 * j);
    }
    out[i] = u;
  }
}

// ---------------- transpose W_skip (f32 in) -> bf16 out, out[c][r]=in[r][c] ----------------
__global__ void k_transpose_bf(const float* __restrict__ in, unsigned short* __restrict__ out, int n) {
  __shared__ float tile[32][33];
  int bx = blockIdx.x * 32, by = blockIdx.y * 32;
  int tx = threadIdx.x, ty = threadIdx.y;
  tile[ty][tx] = in[(size_t)(by + ty) * n + bx + tx];
  __syncthreads();
  out[(size_t)(bx + ty) * n + by + tx] = f2bf(tile[tx][ty]);
}

// ---------------- variance pass 1 ----------------
__global__ __launch_bounds__(256) void k_var1(const float* __restrict__ x, float* colsum, float* colsq) {
  int g = blockIdx.x;
  int t = threadIdx.x;
  float s[4] = {0,0,0,0}, q[4] = {0,0,0,0};
  for (int r = 0; r < 32; r++) {
    const float* rp = x + (size_t)(g * 32 + r) * D_IN;
    #pragma unroll
    for (int j = 0; j < 4; j++) {
      float v = rp[t + 256 * j];
      s[j] += v; q[j] += v * v;
    }
  }
  #pragma unroll
  for (int j = 0; j < 4; j++) {
    atomicAdd(&colsum[t + 256 * j], s[j]);
    atomicAdd(&colsq [t + 256 * j], q[j]);
  }
}

// ---------------- variance pass 2 ----------------
__global__ __launch_bounds__(256) void k_var2(const float* colsum, const float* colsq, float* scal) {
  __shared__ float red[4];
  int t = threadIdx.x;
  float loc = 0.f;
  #pragma unroll
  for (int j = 0; j < 4; j++) {
    int c = t + 256 * j;
    float cs = colsum[c], cq = colsq[c];
    loc += cq - cs * cs * (1.f / (float)B_ROWS);
  }
  loc = waveSum(loc);
  if ((t & 63) == 0) red[t >> 6] = loc;
  __syncthreads();
  if (t == 0) scal[1] = red[0] + red[1] + red[2] + red[3];
}

// =================================================================================
// 128x128-tile, 256-thread (4-wave), triple-buffered FP8 encoder GEMM, BK=64.
// MX-scaled path: mfma_scale_f32_32x32x64_f8f6f4 with unit scales (E8M0 0x7F = 1.0).
// =================================================================================
__device__ __forceinline__ void stage_half8(const unsigned char* __restrict__ G,
                                            int Kb, int r0, int k0b,
                                            unsigned char* buf, int t) {
  #pragma unroll
  for (int j = 0; j < 2; j++) {
    int q = j * 256 + t;                // 512 x 16B = 8KB (128 rows x 64B)
    int row = q >> 2, u = q & 3;
    int uu = u ^ ((row >> 1) & 3);
    gl_lds16(&G[(size_t)(r0 + row) * Kb + k0b + uu * 16], &buf[q * 16]);
  }
}

__global__ __launch_bounds__(256, 3) void k_gemm_enc(
    const unsigned char* __restrict__ A8, const unsigned char* __restrict__ B8,
    const float* __restrict__ bias,
    u64* __restrict__ cand, unsigned int* __restrict__ rowcnt,
    int M, int N, int K) {
  __shared__ unsigned char sBuf[3 * 16384];     // 48 KB
  // epilogue aliases (used only after full drain + __syncthreads):
  unsigned int*  stageKey = (unsigned int*)sBuf;                 // 16 KB (128*32 u32)
  unsigned char* stageCol = (unsigned char*)&sBuf[16384];        // 4 KB
  unsigned int*  s_cnt    = (unsigned int*)&sBuf[20480];         // 512 B (128)
  unsigned int*  s_base   = (unsigned int*)&sBuf[21504];         // 512 B (128)

  const int t = threadIdx.x;
  const int w = t >> 6, l = t & 63;
  const int wr = w >> 1, wc = w & 1;           // 2x2 wave grid, wave tile 64x64
  const int lr = l & 31, lh = l >> 5;          // fragment row-in-32, K-half
  const int row0 = blockIdx.y * 128, col0 = blockIdx.x * 128;
  const int Kb = K;                             // bytes per row (fp8)
  const int NT = K >> 6;                        // 16 K-tiles of BK=64

  f32x16 acc[2][2] = {};                        // 2x2 of 32x32 tiles = 64x64/wave

  // prologue: K-tiles 0,1 staged (4 half-stages = 8 loads/thread)
  stage_half8(A8, Kb, row0, 0,   sBuf + 0,             t);
  stage_half8(B8, Kb, col0, 0,   sBuf + 8192,          t);
  stage_half8(A8, Kb, row0, 64,  sBuf + 16384,         t);
  stage_half8(B8, Kb, col0, 64,  sBuf + 16384 + 8192,  t);

  // per-lane fragment byte offsets, hoisted out of the loop.
  const int raf = wr * 64 + lr,  swa = (raf >> 1) & 3;
  const int rbf = wc * 64 + lr,  swb = (rbf >> 1) & 3;
  const int uA0 = ((2 * lh)     ^ swa) * 16, uA1 = ((2 * lh + 1) ^ swa) * 16;
  const int uB0 = ((2 * lh)     ^ swb) * 16, uB1 = ((2 * lh + 1) ^ swb) * 16;
  const int offA0 = raf * 64,        offA1 = (raf + 32) * 64;
  const int offB0 = 8192 + rbf * 64, offB1 = 8192 + (rbf + 32) * 64;

  for (int tt = 0; tt < NT; tt++) {
    asm volatile("s_waitcnt vmcnt(4)" ::: "memory");   // tile tt landed; tt+1 in flight
    __builtin_amdgcn_s_barrier();

    int ks = (tt + 2 < NT) ? (tt + 2) : (NT - 1);      // dummy tail restage keeps vmcnt uniform
    unsigned char* nb = sBuf + ((tt + 2) % 3) * 16384;
    stage_half8(A8, Kb, row0, ks * 64, nb, t);
    stage_half8(B8, Kb, col0, ks * 64, nb + 8192, t);

    const unsigned char* cb = sBuf + (tt % 3) * 16384;

    // fragment reads: two ds_read_b128 per 32-row block (lane's 32 contiguous K-bytes)
    union Frag { i32x8 w; i32x4 h[2]; };
    Frag av[2], bv[2];
    av[0].h[0] = *(const i32x4*)&cb[offA0 + uA0];
    av[0].h[1] = *(const i32x4*)&cb[offA0 + uA1];
    av[1].h[0] = *(const i32x4*)&cb[offA1 + uA0];
    av[1].h[1] = *(const i32x4*)&cb[offA1 + uA1];
    bv[0].h[0] = *(const i32x4*)&cb[offB0 + uB0];
    bv[0].h[1] = *(const i32x4*)&cb[offB0 + uB1];
    bv[1].h[0] = *(const i32x4*)&cb[offB1 + uB0];
    bv[1].h[1] = *(const i32x4*)&cb[offB1 + uB1];

    __builtin_amdgcn_s_setprio(1);
    #pragma unroll
    for (int mt = 0; mt < 2; mt++)
      #pragma unroll
      for (int nt = 0; nt < 2; nt++)
        acc[mt][nt] = __builtin_amdgcn_mfma_scale_f32_32x32x64_f8f6f4(
            av[mt].w, bv[nt].w, acc[mt][nt],
            0, 0,                   // cbsz=fp8(e4m3), blgp=fp8(e4m3)
            0, 0x7F7F7F7Fu,         // A scale: byte0, E8M0 127 = 1.0
            0, 0x7F7F7F7Fu);        // B scale: byte0, E8M0 127 = 1.0
    __builtin_amdgcn_s_setprio(0);
  }

  // full drain before reusing LDS for the epilogue stage
  asm volatile("s_waitcnt vmcnt(0) lgkmcnt(0)" ::: "memory");
  __syncthreads();

  if (t < 128) s_cnt[t] = 0u;
  __syncthreads();

  // scan 64 values/thread into LDS stage (cheap LDS atomics only)
  // 32x32 C/D layout: col = lane&31, row = (reg&3) + 8*(reg>>2) + 4*(lane>>5)
  #pragma unroll
  for (int nt = 0; nt < 2; nt++) {
    int cl = wc * 64 + nt * 32 + lr;           // local col 0..127
    float bvs = bias[col0 + cl];
    #pragma unroll
    for (int mt = 0; mt < 2; mt++) {
      int rbase = wr * 64 + mt * 32 + lh * 4;
      #pragma unroll
      for (int i = 0; i < 16; i++) {
        float v = acc[mt][nt][i] + bvs;
        if (v > 1.7f) {
          int r = rbase + (i & 3) + 8 * (i >> 2);
          unsigned int p = atomicAdd(&s_cnt[r], 1u);
          if (p < SLOTS) {
            stageKey[r * SLOTS + p] = sortkey(v);
            stageCol[r * SLOTS + p] = (unsigned char)cl;
          }
        }
      }
    }
  }
  __syncthreads();

  // one global atomic per (block,row): reserve space (poison on overflow)
  if (t < 128) {
    unsigned int c = s_cnt[t];
    if (c > SLOTS)      { atomicAdd(&rowcnt[row0 + t], 4096u); s_base[t] = 0x80000000u; }
    else if (c)         s_base[t] = atomicAdd(&rowcnt[row0 + t], c);
    else                s_base[t] = 0u;
  }
  __syncthreads();

  // batched copy-out of staged candidates
  for (int s = t; s < 128 * SLOTS; s += 256) {
    int r = s >> 5, p = s & (SLOTS - 1);
    unsigned int c = s_cnt[r], g0 = s_base[r];
    if ((unsigned int)p < c && c <= SLOTS && !(g0 & 0x80000000u)) {
      unsigned int g = g0 + (unsigned int)p;
      if (g < CCAP)
        cand[(size_t)(row0 + r) * CCAP + g] =
            ((u64)stageKey[s] << 32) | (unsigned int)(~(unsigned int)(col0 + stageCol[s]));
    }
  }
}

// ---------------- 128x128 GEMM core (BK=64, XOR-swizzled) for the small skip GEMM ----------------
__device__ __forceinline__ void stage_swz(const unsigned short* __restrict__ G, int ld,
                                          int r0, int k0, unsigned short* lds, int t) {
  #pragma unroll
  for (int j = 0; j < 4; j++) {
    int q = j * 256 + t;
    int row = q >> 3, u = q & 7;
    int uu = u ^ (row & 7);
    gl_lds16(&G[(size_t)(r0 + row) * ld + k0 + uu * 8], &lds[q * 8]);
  }
}

__device__ __forceinline__ void gemm_core(
    const unsigned short* __restrict__ A, const unsigned short* __restrict__ Bm,
    unsigned short* sA, unsigned short* sB,
    int row0, int col0, int K, int t, int wr, int wc, int lm, int u0,
    f32x4 acc[4][4]) {
  for (int k0 = 0; k0 < K; k0 += 64) {
    stage_swz(A,  K, row0, k0, sA, t);
    stage_swz(Bm, K, col0, k0, sB, t);
    __syncthreads();
    bf16x8 af[4][2], bfr[4][2];
    #pragma unroll
    for (int i = 0; i < 4; i++) {
      int r = wr * 64 + i * 16 + lm;
      int sw = r & 7;
      af[i][0] = *(const bf16x8*)&sA[r * 64 + ((u0 ^ sw) * 8)];
      af[i][1] = *(const bf16x8*)&sA[r * 64 + (((u0 + 4) ^ sw) * 8)];
    }
    #pragma unroll
    for (int n = 0; n < 4; n++) {
      int r = wc * 64 + n * 16 + lm;
      int sw = r & 7;
      bfr[n][0] = *(const bf16x8*)&sB[r * 64 + ((u0 ^ sw) * 8)];
      bfr[n][1] = *(const bf16x8*)&sB[r * 64 + (((u0 + 4) ^ sw) * 8)];
    }
    #pragma unroll
    for (int i = 0; i < 4; i++)
      #pragma unroll
      for (int n = 0; n < 4; n++) {
        acc[i][n] = __builtin_amdgcn_mfma_f32_16x16x32_bf16(af[i][0], bfr[n][0], acc[i][n], 0, 0, 0);
        acc[i][n] = __builtin_amdgcn_mfma_f32_16x16x32_bf16(af[i][1], bfr[n][1], acc[i][n], 0, 0, 0);
      }
    __syncthreads();
  }
}

// ---------------- skip GEMM: bf16 output ----------------
__global__ __launch_bounds__(256) void k_gemm_skip(
    const unsigned short* __restrict__ A, const unsigned short* __restrict__ Bm,
    const float* __restrict__ bias, unsigned short* __restrict__ Cb,
    int M, int N, int K) {
  __shared__ unsigned short sA[128 * 64];
  __shared__ unsigned short sB[128 * 64];
  const int t = threadIdx.x;
  const int w = t >> 6, l = t & 63;
  const int wr = w >> 1, wc = w & 1;
  const int lm = l & 15, u0 = l >> 4;
  const int row0 = blockIdx.y * 128, col0 = blockIdx.x * 128;

  f32x4 acc[4][4] = {};
  gemm_core(A, Bm, sA, sB, row0, col0, K, t, wr, wc, lm, u0, acc);

  const int lg = l >> 4;
  #pragma unroll
  for (int n = 0; n < 4; n++) {
    int col = col0 + wc * 64 + n * 16 + lm;
    float bv = bias[col];
    #pragma unroll
    for (int i = 0; i < 4; i++) {
      int rbase = row0 + wr * 64 + i * 16 + lg * 4;
      #pragma unroll
      for (int j = 0; j < 4; j++)
        Cb[(size_t)(rbase + j) * N + col] = f2bf(acc[i][n][j] + bv);
    }
  }
}

// ---------------- exact top-k selection; sorted lists; zero-fill early + scatter late ----------------
__global__ __launch_bounds__(256) void k_select(
    const u64* __restrict__ cand, const unsigned int* __restrict__ rowcnt,
    const unsigned char* __restrict__ xf8, const unsigned char* __restrict__ wenc8,
    const float* __restrict__ benc,
    float* __restrict__ menc, uint2* __restrict__ lists, unsigned int* __restrict__ l0p) {
  __shared__ u64 sc[CCAP];               // 8 KB
  __shared__ unsigned int hist[NBIN];    // 8 KB
  __shared__ u64 scratch[256];           // 2 KB (aliased as xrow in fallback)
  __shared__ unsigned int sS[256];       // 1 KB
  __shared__ uint2 win[256];             // 2 KB
  __shared__ int s_bb[3];
  __shared__ unsigned int s_bc[3];
  __shared__ u64 s_T[3];
  __shared__ int s_scnt;
  __shared__ unsigned int s_l0, s_pos;

  const int b = blockIdx.x, t = threadIdx.x;
  float* rowp = menc + (size_t)b * L_DIM;

  int cnt = (int)rowcnt[b];
  if (cnt >= 256 && cnt <= CCAP) {
    for (int i = t; i < cnt; i += 256) sc[i] = cand[(size_t)b * CCAP + i];
    // early coalesced zero-fill of menc row: stores drain under the selection compute
    #pragma unroll 4
    for (int g = 0; g < 16; g++) {
      f32x4 z = {};
      *(f32x4*)&rowp[g * 1024 + t * 4] = z;
    }
    __syncthreads();
  } else {
    // ---- fallback (never expected): recompute pre (fp8 x fp8, identity layout) ----
    unsigned char* xrow = (unsigned char*)scratch;     // 1024 bytes
    for (int i = t; i < D_IN; i += 256) xrow[i] = xf8[(size_t)b * D_IN + i];
    __syncthreads();
    for (int q = 0; q < 64; q++) {
      int lat = q * 256 + t;
      const unsigned char* wp = &wenc8[(size_t)lat * D_IN];
      float a = 0.f;
      for (int k = 0; k < D_IN; k++) a += e4m3f(xrow[k]) * e4m3f(wp[k]);
      rowp[lat] = a + benc[lat];           // rowp used as scratch
    }
    __syncthreads();
    float T = 1.7f;
    for (int at = 0; at < 10; at++) {
      if (t == 0) s_scnt = 0;
      __syncthreads();
      int loc = 0;
      for (int q = 0; q < 64; q++) loc += (rowp[q * 256 + t] > T) ? 1 : 0;
      atomicAdd(&s_scnt, loc);
      __syncthreads();
      int c2 = s_scnt;
      if (c2 >= 256 && c2 <= CCAP) break;
      T = (c2 < 256) ? (T - 0.5f) : (T + 0.3f);
      __syncthreads();
    }
    if (t == 0) s_scnt = 0;
    __syncthreads();
    for (int q = 0; q < 64; q++) {
      int lat = q * 256 + t;
      float v = rowp[lat];
      if (v > T) {
        int p = atomicAdd(&s_scnt, 1);
        if (p < CCAP) sc[p] = ((u64)sortkey(v) << 32) | (unsigned int)(~(unsigned int)lat);
      }
    }
    __syncthreads();
    cnt = min(s_scnt, CCAP);
    for (int i = t * 4; i < L_DIM; i += 1024) { f32x4 z = {}; *(f32x4*)&rowp[i] = z; }
    __syncthreads();
  }

  // histogram over candidate values
  for (int i = t; i < NBIN; i += 256) hist[i] = 0u;
  __syncthreads();
  for (int i = t; i < cnt; i += 256) {
    float v = keyval((unsigned int)(sc[i] >> 32));
    atomicAdd(&hist[binof(v)], 1u);
  }
  __syncthreads();

  // suffix counts
  unsigned int csum = 0;
  #pragma unroll
  for (int j = 0; j < 8; j++) csum += hist[t * 8 + j];
  sS[t] = csum;
  __syncthreads();
  for (int off = 1; off < 256; off <<= 1) {
    unsigned int v2 = (t + off < 256) ? sS[t + off] : 0u;
    __syncthreads();
    sS[t] += v2;
    __syncthreads();
  }
  {
    unsigned int above = (t < 255) ? sS[t + 1] : 0u;
    unsigned int run = 0;
    for (int j = 7; j >= 0; j--) {
      int bb = t * 8 + j;
      unsigned int S = above + run, h = hist[bb];
      if (h) {
        if (S < 32u  && 32u  <= S + h) { s_bb[0] = bb; s_bc[0] = S; }
        if (S < 128u && 128u <= S + h) { s_bb[1] = bb; s_bc[1] = S; }
        if (S < 256u && 256u <= S + h) { s_bb[2] = bb; s_bc[2] = S; }
      }
      run += h;
    }
  }
  __syncthreads();

  // resolve exact threshold ukeys inside each boundary bin
  for (int ri = 0; ri < 3; ri++) {
    const int r = (ri == 0) ? 32 : (ri == 1) ? 128 : 256;
    int bb = s_bb[ri];
    int cA = (int)s_bc[ri];
    if (t == 0) s_scnt = 0;
    __syncthreads();
    for (int i = t; i < cnt; i += 256) {
      float v = keyval((unsigned int)(sc[i] >> 32));
      if (binof(v) == bb) {
        int p = atomicAdd(&s_scnt, 1);
        if (p < 256) scratch[p] = sc[i];
      }
    }
    __syncthreads();
    int m = min(s_scnt, 256);
    for (int i = t; i < m; i += 256) {
      u64 me = scratch[i];
      int rk = 0;
      for (int j2 = 0; j2 < m; j2++) rk += (scratch[j2] > me) ? 1 : 0;
      if (rk == r - cA - 1) s_T[ri] = me;
    }
    __syncthreads();
  }

  // classify candidates, collect winners into win[]
  if (t == 0) { s_pos = 0u; s_l0 = 0u; }
  __syncthreads();
  const u64 T32 = s_T[0], T128 = s_T[1], T256 = s_T[2];
  for (int i = t; i < cnt; i += 256) {
    u64 e = sc[i];
    int w = (e >= T32) ? 3 : (e >= T128) ? 2 : (e >= T256) ? 1 : 0;
    if (w) {
      unsigned int p = atomicAdd(&s_pos, 1u);
      int idx = (int)(~(unsigned int)e) & (L_DIM - 1);
      float v = keyval((unsigned int)(e >> 32));
      float rv = fmaxf(v, 0.f);
      if (p < 256u)
        win[p] = make_uint2((unsigned int)idx | ((unsigned int)w << 20), __float_as_uint(rv));
      if (rv > 0.f) atomicAdd(&s_l0, 1u);
    }
  }
  __syncthreads();
  // pad (sorts last; weight bits decode to 0 -> scatter writes 0, harmless)
  for (int i = (int)s_pos + t; i < 256; i += 256) win[i] = make_uint2(0xFFFFFu, 0u);
  __syncthreads();

  // bitonic sort win[] ascending by latent idx
  for (int k = 2; k <= 256; k <<= 1) {
    for (int j = k >> 1; j > 0; j >>= 1) {
      int x = t ^ j;
      if (x > t) {
        uint2 a = win[t], bb2 = win[x];
        bool asc = ((t & k) == 0);
        bool swap = asc ? ((a.x & 0xFFFFFu) > (bb2.x & 0xFFFFFu))
                        : ((a.x & 0xFFFFFu) < (bb2.x & 0xFFFFFu));
        if (swap) { win[t] = bb2; win[x] = a; }
      }
      __syncthreads();
    }
  }

  lists[(size_t)b * 256 + t] = win[t];

  // scatter winners over the (already drained) zeroed row: one 4B store per thread
  {
    uint2 e = win[t];
    int idx = (int)(e.x & 0xFFFFFu) & (L_DIM - 1);
    unsigned int wg = (e.x >> 20) & 3u;
    float rv = __uint_as_float(e.y);
    rowp[idx] = rv * (float)wg * (1.f / 3.f);
  }

  if (t == 0) atomicAdd(l0p, s_l0);
}

// ---------------- sparse decode: int8 W_dec gather, 512 thr, 4 groups ----------------
// r6 structure, gather depth 8 -> 16 (Little's law: latency-bound gather stream,
// more outstanding loads -> more throughput). Same scalar-base addressing via
// readfirstlane; straight-line macro body (no lambdas, no runtime-indexed arrays).
// Accumulation order per class per thread unchanged -> bit-identical output vs r6.
#define DEC_PROC(E, Q)                                             \
  do {                                                             \
    int wgt_ = (int)(((E).x >> 20) & 3u);                          \
    float v_ = __uint_as_float((E).y) * (1.0f / W8SCALE);          \
    float f_[8];                                                   \
    _Pragma("unroll")                                              \
    for (int j_ = 0; j_ < 4; j_++) {                               \
      f_[j_]     = (float)((int)((Q).x << (24 - 8 * j_)) >> 24);   \
      f_[4 + j_] = (float)((int)((Q).y << (24 - 8 * j_)) >> 24);   \
    }                                                              \
    if (wgt_ == 3) {                                               \
      _Pragma("unroll")                                            \
      for (int j_ = 0; j_ < 8; j_++) a1[j_] += v_ * f_[j_];        \
    } else if (wgt_ == 2) {                                        \
      _Pragma("unroll")                                            \
      for (int j_ = 0; j_ < 8; j_++) a2[j_] += v_ * f_[j_];        \
    } else {                                                       \
      _Pragma("unroll")                                            \
      for (int j_ = 0; j_ < 8; j_++) a3[j_] += v_ * f_[j_];        \
    }                                                              \
  } while (0)

#define DEC_ENT(n)                                                                  \
  uint2 e##n = ll[4 * (i0 + n) + grp];                                              \
  const unsigned char* r##n##p = W8 +                                               \
      (size_t)((unsigned)__builtin_amdgcn_readfirstlane(e##n.x) & (L_DIM - 1)) * D_IN;

__global__ __launch_bounds__(512) void k_decode(
    const uint2* __restrict__ lists, const unsigned char* __restrict__ W8,
    const unsigned short* __restrict__ skipb, const float* __restrict__ mlp,
    float* __restrict__ mdec, float* __restrict__ loss_acc) {
  __shared__ uint2 ll[256];
  __shared__ float part[3][24][128];   // [group-1][class*8+col][lane] - stride-1 in lane
  __shared__ float red[2];
  const int b = blockIdx.x, t = threadIdx.x;
  if (t < 256) ll[t] = lists[(size_t)b * 256 + t];
  __syncthreads();

  const int lane = t & 127, grp = t >> 7;   // 4 groups x 128 lanes
  const int c = lane * 8;                   // loop-invariant voffset (bytes)

  float a1[8] = {}, a2[8] = {}, a3[8] = {};

  // group grp processes sorted entries 4i+grp; batches of 16 independent gathers
  for (int i0 = 0; i0 < 64; i0 += 16) {
    DEC_ENT(0)  DEC_ENT(1)  DEC_ENT(2)  DEC_ENT(3)
    DEC_ENT(4)  DEC_ENT(5)  DEC_ENT(6)  DEC_ENT(7)
    DEC_ENT(8)  DEC_ENT(9)  DEC_ENT(10) DEC_ENT(11)
    DEC_ENT(12) DEC_ENT(13) DEC_ENT(14) DEC_ENT(15)
    // 16 independent gathers in flight
    uint2 q0  = *(const uint2*)(r0p  + c);
    uint2 q1  = *(const uint2*)(r1p  + c);
    uint2 q2  = *(const uint2*)(r2p  + c);
    uint2 q3  = *(const uint2*)(r3p  + c);
    uint2 q4  = *(const uint2*)(r4p  + c);
    uint2 q5  = *(const uint2*)(r5p  + c);
    uint2 q6  = *(const uint2*)(r6p  + c);
    uint2 q7  = *(const uint2*)(r7p  + c);
    uint2 q8  = *(const uint2*)(r8p  + c);
    uint2 q9  = *(const uint2*)(r9p  + c);
    uint2 q10 = *(const uint2*)(r10p + c);
    uint2 q11 = *(const uint2*)(r11p + c);
    uint2 q12 = *(const uint2*)(r12p + c);
    uint2 q13 = *(const uint2*)(r13p + c);
    uint2 q14 = *(const uint2*)(r14p + c);
    uint2 q15 = *(const uint2*)(r15p + c);
    DEC_PROC(e0, q0);   DEC_PROC(e1, q1);   DEC_PROC(e2, q2);   DEC_PROC(e3, q3);
    DEC_PROC(e4, q4);   DEC_PROC(e5, q5);   DEC_PROC(e6, q6);   DEC_PROC(e7, q7);
    DEC_PROC(e8, q8);   DEC_PROC(e9, q9);   DEC_PROC(e10, q10); DEC_PROC(e11, q11);
    DEC_PROC(e12, q12); DEC_PROC(e13, q13); DEC_PROC(e14, q14); DEC_PROC(e15, q15);
  }

  if (grp != 0) {
    #pragma unroll
    for (int j = 0; j < 8; j++) {
      part[grp - 1][j][lane]      = a1[j];
      part[grp - 1][8 + j][lane]  = a2[j];
      part[grp - 1][16 + j][lane] = a3[j];
    }
  }
  __syncthreads();

  float lsum = 0.f;
  if (grp == 0) {
    #pragma unroll
    for (int g = 0; g < 3; g++) {
      #pragma unroll
      for (int j = 0; j < 8; j++) {
        a1[j] += part[g][j][lane];
        a2[j] += part[g][8 + j][lane];
        a3[j] += part[g][16 + j][lane];
      }
    }
    u16x8 skv = *(const u16x8*)&skipb[(size_t)b * D_IN + c];
    f32x4 m0 = *(const f32x4*)&mlp[(size_t)b * D_IN + c];
    f32x4 m1 = *(const f32x4*)&mlp[(size_t)b * D_IN + c + 4];
    float mm[8] = {m0[0], m0[1], m0[2], m0[3], m1[0], m1[1], m1[2], m1[3]};
    float md[8];
    #pragma unroll
    for (int j = 0; j < 8; j++) {
      float sk   = bf2f(skv[j]);
      float d32  = sk + a1[j];
      float d128 = d32 + a2[j];
      float d256 = d128 + a3[j];
      md[j] = (d32 + d128 + d256) * (1.f / 3.f);
      float e1 = mm[j] - d32, e2 = mm[j] - d128, e3 = mm[j] - d256;
      lsum += e1 * e1 + e2 * e2 + e3 * e3;
    }
    f32x4 o0 = {md[0], md[1], md[2], md[3]};
    f32x4 o1 = {md[4], md[5], md[6], md[7]};
    *(f32x4*)&mdec[(size_t)b * D_IN + c]     = o0;
    *(f32x4*)&mdec[(size_t)b * D_IN + c + 4] = o1;
  }

  lsum = waveSum(lsum);                 // waves 2..7 sum to 0
  if ((t & 63) == 0 && t < 128) red[t >> 6] = lsum;
  __syncthreads();
  if (t == 0) atomicAdd(loss_acc, red[0] + red[1]);
}

// ---------------- finalize scalars ----------------
__global__ void k_final(const float* scal, const unsigned int* l0p, float* outscal) {
  outscal[0] = scal[0] / scal[1];
  outscal[1] = (float)(*l0p);
}

// ---------------- host launch ----------------
extern "C" void kernel_launch(void* const* d_in, const int* in_sizes, int n_in,
                              void* d_out, int out_size, void* d_ws, size_t ws_size,
                              hipStream_t stream) {
  (void)in_sizes; (void)n_in; (void)out_size; (void)ws_size;
  const float* x     = (const float*)d_in[0];
  const float* mlp   = (const float*)d_in[1];
  const float* Wenc  = (const float*)d_in[2];
  const float* benc  = (const float*)d_in[3];
  const float* Wdec  = (const float*)d_in[4];
  const float* bdec  = (const float*)d_in[5];
  const float* Wskip = (const float*)d_in[6];

  char* ws = (char*)d_ws;
  float*          scal    = (float*)(ws + 0);                 // [0]=loss [1]=var
  unsigned int*   l0p     = (unsigned int*)(ws + 8);
  float*          colsum  = (float*)(ws + 256);
  float*          colsq   = (float*)(ws + 4352);
  unsigned int*   rowcnt  = (unsigned int*)(ws + 8448);        // 16 KB
  unsigned short* xb      = (unsigned short*)(ws + 24832);     // 8 MB (bf16, for skip GEMM)
  unsigned char*  wenc8   = (unsigned char*)(ws + 8413440);    // 16 MB (fp8 W_enc, identity)
  unsigned char*  xf8     = (unsigned char*)(ws + 8413440 + 16777216);  // 4 MB (fp8 x, identity)
  unsigned short* wsktb   = (unsigned short*)(ws + 41967872);  // 2 MB
  unsigned short* skipb   = (unsigned short*)(ws + 44065024);  // 8 MB (bf16)
  uint2*          lists   = (uint2*)(ws + 52453632);           // 8 MB
  u64*            cand    = (u64*)(ws + 60842240);             // 32 MB
  unsigned char*  wdec8   = (unsigned char*)(ws + 60842240);   // 16 MB, aliases cand (after select)

  float* out  = (float*)d_out;
  float* menc = out;
  float* mdec = out + (size_t)B_ROWS * L_DIM;
  float* oscl = out + (size_t)B_ROWS * L_DIM + (size_t)B_ROWS * D_IN;

  k_zero<<<16, 256, 0, stream>>>(scal, colsum, colsq, rowcnt);
  k_convert<<<2048, 256, 0, stream>>>(x, xb, (B_ROWS * D_IN) / 4);
  k_convert_fp8<<<1024, 256, 0, stream>>>(x,    xf8,   (B_ROWS * D_IN) / 4);
  k_convert_fp8<<<2048, 256, 0, stream>>>(Wenc, wenc8, (L_DIM * D_IN) / 4);
  k_transpose_bf<<<dim3(32, 32), dim3(32, 32), 0, stream>>>(Wskip, wsktb, D_IN);
  k_var1<<<128, 256, 0, stream>>>(x, colsum, colsq);
  k_var2<<<1, 256, 0, stream>>>(colsum, colsq, scal);
  k_gemm_enc<<<dim3(L_DIM / 128, B_ROWS / 128), 256, 0, stream>>>(
      xf8, wenc8, benc, cand, rowcnt, B_ROWS, L_DIM, D_IN);
  k_gemm_skip<<<dim3(D_IN / 128, B_ROWS / 128), 256, 0, stream>>>(
      xb, wsktb, bdec, skipb, B_ROWS, D_IN, D_IN);
  k_select<<<B_ROWS, 256, 0, stream>>>(cand, rowcnt, xf8, wenc8, benc, menc, lists, l0p);
  k_convert_i8<<<2048, 256, 0, stream>>>(Wdec, (unsigned int*)wdec8, (L_DIM * D_IN) / 4);  // aliases cand
  k_decode<<<B_ROWS, 512, 0, stream>>>(lists, wdec8, skipb, mlp, mdec, scal);
  k_final<<<1, 1, 0, stream>>>(scal, l0p, oscl);
}

// Round 8
// 456.856 us; speedup vs baseline: 1.0393x; 1.0393x over previous
//
#include <hip/hip_runtime.h>
#include <stdint.h>

// ---------------- types ----------------
typedef short   bf16x8 __attribute__((ext_vector_type(8)));
typedef float   f32x4  __attribute__((ext_vector_type(4)));
typedef float   f32x16 __attribute__((ext_vector_type(16)));
typedef int     i32x4  __attribute__((ext_vector_type(4)));
typedef int     i32x8  __attribute__((ext_vector_type(8)));
typedef unsigned short u16x8 __attribute__((ext_vector_type(8)));
typedef unsigned long long u64;
typedef long long i64;
typedef long long i64x2 __attribute__((ext_vector_type(2)));

#define B_ROWS 4096
#define D_IN   1024
#define L_DIM  16384
#define NBIN   2048
#define CCAP   1024
#define SLOTS  32
#define W8SCALE 1200.0f

// ---------------- helpers ----------------
__device__ __forceinline__ unsigned short f2bf(float f) {
  unsigned int u = __float_as_uint(f);
  u = (u + 0x7FFFu + ((u >> 16) & 1u)) >> 16;   // RNE to bf16
  return (unsigned short)u;
}
__device__ __forceinline__ float bf2f(unsigned short h) {
  return __uint_as_float(((unsigned int)h) << 16);
}
// f32 -> OCP e4m3fn (RNE, flush exp<=0 to 0, clamp 448)
__device__ __forceinline__ unsigned char f2e4m3(float v) {
  unsigned int u = __float_as_uint(v);
  unsigned int s = (u >> 24) & 0x80u;
  unsigned int a = u & 0x7FFFFFFFu;
  unsigned int r = (a + 0x0007FFFFu + ((a >> 20) & 1u)) >> 20;   // (exp<<3)|man, rounded
  if (r <= (120u << 3)) return (unsigned char)s;                 // underflow -> +-0
  r -= (120u << 3);
  if (r > 0x7Eu) r = 0x7Eu;                                      // clamp to 448
  return (unsigned char)(s | r);
}
__device__ __forceinline__ float e4m3f(unsigned char b) {
  unsigned int e = (b >> 3) & 0xFu, m = b & 7u, s = ((unsigned int)b & 0x80u) << 24;
  if (e == 0) return __uint_as_float(s);
  return __uint_as_float(s | ((e + 120u) << 23) | (m << 20));
}
__device__ __forceinline__ unsigned int sortkey(float f) {
  unsigned int u = __float_as_uint(f);
  return (u & 0x80000000u) ? ~u : (u | 0x80000000u);
}
__device__ __forceinline__ float keyval(unsigned int k) {
  unsigned int u = (k & 0x80000000u) ? (k & 0x7FFFFFFFu) : ~k;
  return __uint_as_float(u);
}
__device__ __forceinline__ int binof(float v) {
  int b = (int)((v + 2.0f) * (2048.0f / 7.0f));
  return b < 0 ? 0 : (b > 2047 ? 2047 : b);
}
__device__ __forceinline__ void gl_lds16(const void* g, void* l) {
  __builtin_amdgcn_global_load_lds(
      (const __attribute__((address_space(1))) unsigned int*)g,
      (__attribute__((address_space(3))) unsigned int*)l, 16, 0, 0);
}
__device__ __forceinline__ float waveSum(float v) {
  #pragma unroll
  for (int m = 32; m; m >>= 1) v += __shfl_xor(v, m);
  return v;
}

// ---------------- fused prep: zero bookkeeping + x -> bf16 + x -> fp8 (one x pass) ----------
// Same 2048-block grid-stride access pattern as the proven separate converts (r2's failed
// fusion used block-sequential rows + var atomics; this changes ONLY output count).
__global__ void k_prep(const float* __restrict__ x,
                       unsigned short* __restrict__ xb, unsigned char* __restrict__ xf8,
                       float* scal, float* colsum, float* colsq, unsigned int* rowcnt,
                       int n4) {
  int gt = blockIdx.x * blockDim.x + threadIdx.x;
  if (gt < 8) scal[gt] = 0.f;              // [0]=loss, [1]=var
  if (gt < 1024) { colsum[gt] = 0.f; colsq[gt] = 0.f; }
  if (gt < B_ROWS) rowcnt[gt] = 0u;
  int stride = gridDim.x * blockDim.x;
  for (int i = gt; i < n4; i += stride) {
    f32x4 v = *((const f32x4*)x + i);
    ushort4 o;
    o.x = f2bf(v[0]); o.y = f2bf(v[1]); o.z = f2bf(v[2]); o.w = f2bf(v[3]);
    *((ushort4*)xb + i) = o;
    unsigned int u = 0;
    #pragma unroll
    for (int j = 0; j < 4; j++) u |= ((unsigned int)f2e4m3(v[j])) << (8 * j);
    *((unsigned int*)xf8 + i) = u;
  }
}

// ---------------- convert f32 -> fp8 e4m3, IDENTITY layout (W_enc) ----------------
__global__ void k_convert_fp8(const float* __restrict__ in, unsigned char* __restrict__ out, int n4) {
  int i = blockIdx.x * blockDim.x + threadIdx.x;
  int stride = gridDim.x * blockDim.x;
  for (; i < n4; i += stride) {
    f32x4 v = *((const f32x4*)in + i);
    unsigned int u = 0;
    #pragma unroll
    for (int j = 0; j < 4; j++) u |= ((unsigned int)f2e4m3(v[j])) << (8 * j);
    *((unsigned int*)out + i) = u;
  }
}

// ---------------- convert f32 -> int8 (scale W8SCALE, clamp +-127), packed 4/word ----------------
__global__ void k_convert_i8(const float* __restrict__ in, unsigned int* __restrict__ out, int n4) {
  int i = blockIdx.x * blockDim.x + threadIdx.x;
  int stride = gridDim.x * blockDim.x;
  for (; i < n4; i += stride) {
    f32x4 v = *((const f32x4*)in + i);
    unsigned int u = 0;
    #pragma unroll
    for (int j = 0; j < 4; j++) {
      int q = (int)rintf(v[j] * W8SCALE);
      q = q > 127 ? 127 : (q < -127 ? -127 : q);
      u |= ((unsigned int)q & 0xFFu) << (8 * j);
    }
    out[i] = u;
  }
}

// ---------------- transpose W_skip (f32 in) -> bf16 out, out[c][r]=in[r][c] ----------------
__global__ void k_transpose_bf(const float* __restrict__ in, unsigned short* __restrict__ out, int n) {
  __shared__ float tile[32][33];
  int bx = blockIdx.x * 32, by = blockIdx.y * 32;
  int tx = threadIdx.x, ty = threadIdx.y;
  tile[ty][tx] = in[(size_t)(by + ty) * n + bx + tx];
  __syncthreads();
  out[(size_t)(bx + ty) * n + by + tx] = f2bf(tile[tx][ty]);
}

// ---------------- variance pass 1 ----------------
__global__ __launch_bounds__(256) void k_var1(const float* __restrict__ x, float* colsum, float* colsq) {
  int g = blockIdx.x;
  int t = threadIdx.x;
  float s[4] = {0,0,0,0}, q[4] = {0,0,0,0};
  for (int r = 0; r < 32; r++) {
    const float* rp = x + (size_t)(g * 32 + r) * D_IN;
    #pragma unroll
    for (int j = 0; j < 4; j++) {
      float v = rp[t + 256 * j];
      s[j] += v; q[j] += v * v;
    }
  }
  #pragma unroll
  for (int j = 0; j < 4; j++) {
    atomicAdd(&colsum[t + 256 * j], s[j]);
    atomicAdd(&colsq [t + 256 * j], q[j]);
  }
}

// ---------------- variance pass 2 ----------------
__global__ __launch_bounds__(256) void k_var2(const float* colsum, const float* colsq, float* scal) {
  __shared__ float red[4];
  int t = threadIdx.x;
  float loc = 0.f;
  #pragma unroll
  for (int j = 0; j < 4; j++) {
    int c = t + 256 * j;
    float cs = colsum[c], cq = colsq[c];
    loc += cq - cs * cs * (1.f / (float)B_ROWS);
  }
  loc = waveSum(loc);
  if ((t & 63) == 0) red[t >> 6] = loc;
  __syncthreads();
  if (t == 0) scal[1] = red[0] + red[1] + red[2] + red[3];
}

// =================================================================================
// 128x128-tile, 256-thread (4-wave), triple-buffered FP8 encoder GEMM, BK=64.
// MX-scaled path: mfma_scale_f32_32x32x64_f8f6f4 with unit scales (E8M0 0x7F = 1.0).
// =================================================================================
__device__ __forceinline__ void stage_half8(const unsigned char* __restrict__ G,
                                            int Kb, int r0, int k0b,
                                            unsigned char* buf, int t) {
  #pragma unroll
  for (int j = 0; j < 2; j++) {
    int q = j * 256 + t;                // 512 x 16B = 8KB (128 rows x 64B)
    int row = q >> 2, u = q & 3;
    int uu = u ^ ((row >> 1) & 3);
    gl_lds16(&G[(size_t)(r0 + row) * Kb + k0b + uu * 16], &buf[q * 16]);
  }
}

__global__ __launch_bounds__(256, 3) void k_gemm_enc(
    const unsigned char* __restrict__ A8, const unsigned char* __restrict__ B8,
    const float* __restrict__ bias,
    u64* __restrict__ cand, unsigned int* __restrict__ rowcnt,
    int M, int N, int K) {
  __shared__ unsigned char sBuf[3 * 16384];     // 48 KB
  // epilogue aliases (used only after full drain + __syncthreads):
  unsigned int*  stageKey = (unsigned int*)sBuf;                 // 16 KB (128*32 u32)
  unsigned char* stageCol = (unsigned char*)&sBuf[16384];        // 4 KB
  unsigned int*  s_cnt    = (unsigned int*)&sBuf[20480];         // 512 B (128)
  unsigned int*  s_base   = (unsigned int*)&sBuf[21504];         // 512 B (128)

  const int t = threadIdx.x;
  const int w = t >> 6, l = t & 63;
  const int wr = w >> 1, wc = w & 1;           // 2x2 wave grid, wave tile 64x64
  const int lr = l & 31, lh = l >> 5;          // fragment row-in-32, K-half
  const int row0 = blockIdx.y * 128, col0 = blockIdx.x * 128;
  const int Kb = K;                             // bytes per row (fp8)
  const int NT = K >> 6;                        // 16 K-tiles of BK=64

  f32x16 acc[2][2] = {};                        // 2x2 of 32x32 tiles = 64x64/wave

  // prologue: K-tiles 0,1 staged (4 half-stages = 8 loads/thread)
  stage_half8(A8, Kb, row0, 0,   sBuf + 0,             t);
  stage_half8(B8, Kb, col0, 0,   sBuf + 8192,          t);
  stage_half8(A8, Kb, row0, 64,  sBuf + 16384,         t);
  stage_half8(B8, Kb, col0, 64,  sBuf + 16384 + 8192,  t);

  // per-lane fragment byte offsets, hoisted out of the loop.
  const int raf = wr * 64 + lr,  swa = (raf >> 1) & 3;
  const int rbf = wc * 64 + lr,  swb = (rbf >> 1) & 3;
  const int uA0 = ((2 * lh)     ^ swa) * 16, uA1 = ((2 * lh + 1) ^ swa) * 16;
  const int uB0 = ((2 * lh)     ^ swb) * 16, uB1 = ((2 * lh + 1) ^ swb) * 16;
  const int offA0 = raf * 64,        offA1 = (raf + 32) * 64;
  const int offB0 = 8192 + rbf * 64, offB1 = 8192 + (rbf + 32) * 64;

  for (int tt = 0; tt < NT; tt++) {
    asm volatile("s_waitcnt vmcnt(4)" ::: "memory");   // tile tt landed; tt+1 in flight
    __builtin_amdgcn_s_barrier();

    int ks = (tt + 2 < NT) ? (tt + 2) : (NT - 1);      // dummy tail restage keeps vmcnt uniform
    unsigned char* nb = sBuf + ((tt + 2) % 3) * 16384;
    stage_half8(A8, Kb, row0, ks * 64, nb, t);
    stage_half8(B8, Kb, col0, ks * 64, nb + 8192, t);

    const unsigned char* cb = sBuf + (tt % 3) * 16384;

    // fragment reads: two ds_read_b128 per 32-row block (lane's 32 contiguous K-bytes)
    union Frag { i32x8 w; i32x4 h[2]; };
    Frag av[2], bv[2];
    av[0].h[0] = *(const i32x4*)&cb[offA0 + uA0];
    av[0].h[1] = *(const i32x4*)&cb[offA0 + uA1];
    av[1].h[0] = *(const i32x4*)&cb[offA1 + uA0];
    av[1].h[1] = *(const i32x4*)&cb[offA1 + uA1];
    bv[0].h[0] = *(const i32x4*)&cb[offB0 + uB0];
    bv[0].h[1] = *(const i32x4*)&cb[offB0 + uB1];
    bv[1].h[0] = *(const i32x4*)&cb[offB1 + uB0];
    bv[1].h[1] = *(const i32x4*)&cb[offB1 + uB1];

    __builtin_amdgcn_s_setprio(1);
    #pragma unroll
    for (int mt = 0; mt < 2; mt++)
      #pragma unroll
      for (int nt = 0; nt < 2; nt++)
        acc[mt][nt] = __builtin_amdgcn_mfma_scale_f32_32x32x64_f8f6f4(
            av[mt].w, bv[nt].w, acc[mt][nt],
            0, 0,                   // cbsz=fp8(e4m3), blgp=fp8(e4m3)
            0, 0x7F7F7F7Fu,         // A scale: byte0, E8M0 127 = 1.0
            0, 0x7F7F7F7Fu);        // B scale: byte0, E8M0 127 = 1.0
    __builtin_amdgcn_s_setprio(0);
  }

  // full drain before reusing LDS for the epilogue stage
  asm volatile("s_waitcnt vmcnt(0) lgkmcnt(0)" ::: "memory");
  __syncthreads();

  if (t < 128) s_cnt[t] = 0u;
  __syncthreads();

  // scan 64 values/thread into LDS stage (cheap LDS atomics only)
  // 32x32 C/D layout: col = lane&31, row = (reg&3) + 8*(reg>>2) + 4*(lane>>5)
  #pragma unroll
  for (int nt = 0; nt < 2; nt++) {
    int cl = wc * 64 + nt * 32 + lr;           // local col 0..127
    float bvs = bias[col0 + cl];
    #pragma unroll
    for (int mt = 0; mt < 2; mt++) {
      int rbase = wr * 64 + mt * 32 + lh * 4;
      #pragma unroll
      for (int i = 0; i < 16; i++) {
        float v = acc[mt][nt][i] + bvs;
        if (v > 1.7f) {
          int r = rbase + (i & 3) + 8 * (i >> 2);
          unsigned int p = atomicAdd(&s_cnt[r], 1u);
          if (p < SLOTS) {
            stageKey[r * SLOTS + p] = sortkey(v);
            stageCol[r * SLOTS + p] = (unsigned char)cl;
          }
        }
      }
    }
  }
  __syncthreads();

  // one global atomic per (block,row): reserve space (poison on overflow)
  if (t < 128) {
    unsigned int c = s_cnt[t];
    if (c > SLOTS)      { atomicAdd(&rowcnt[row0 + t], 4096u); s_base[t] = 0x80000000u; }
    else if (c)         s_base[t] = atomicAdd(&rowcnt[row0 + t], c);
    else                s_base[t] = 0u;
  }
  __syncthreads();

  // batched copy-out of staged candidates
  for (int s = t; s < 128 * SLOTS; s += 256) {
    int r = s >> 5, p = s & (SLOTS - 1);
    unsigned int c = s_cnt[r], g0 = s_base[r];
    if ((unsigned int)p < c && c <= SLOTS && !(g0 & 0x80000000u)) {
      unsigned int g = g0 + (unsigned int)p;
      if (g < CCAP)
        cand[(size_t)(row0 + r) * CCAP + g] =
            ((u64)stageKey[s] << 32) | (unsigned int)(~(unsigned int)(col0 + stageCol[s]));
    }
  }
}

// ---------------- 128x128 GEMM core (BK=64, XOR-swizzled) for the small skip GEMM ----------------
__device__ __forceinline__ void stage_swz(const unsigned short* __restrict__ G, int ld,
                                          int r0, int k0, unsigned short* lds, int t) {
  #pragma unroll
  for (int j = 0; j < 4; j++) {
    int q = j * 256 + t;
    int row = q >> 3, u = q & 7;
    int uu = u ^ (row & 7);
    gl_lds16(&G[(size_t)(r0 + row) * ld + k0 + uu * 8], &lds[q * 8]);
  }
}

__device__ __forceinline__ void gemm_core(
    const unsigned short* __restrict__ A, const unsigned short* __restrict__ Bm,
    unsigned short* sA, unsigned short* sB,
    int row0, int col0, int K, int t, int wr, int wc, int lm, int u0,
    f32x4 acc[4][4]) {
  for (int k0 = 0; k0 < K; k0 += 64) {
    stage_swz(A,  K, row0, k0, sA, t);
    stage_swz(Bm, K, col0, k0, sB, t);
    __syncthreads();
    bf16x8 af[4][2], bfr[4][2];
    #pragma unroll
    for (int i = 0; i < 4; i++) {
      int r = wr * 64 + i * 16 + lm;
      int sw = r & 7;
      af[i][0] = *(const bf16x8*)&sA[r * 64 + ((u0 ^ sw) * 8)];
      af[i][1] = *(const bf16x8*)&sA[r * 64 + (((u0 + 4) ^ sw) * 8)];
    }
    #pragma unroll
    for (int n = 0; n < 4; n++) {
      int r = wc * 64 + n * 16 + lm;
      int sw = r & 7;
      bfr[n][0] = *(const bf16x8*)&sB[r * 64 + ((u0 ^ sw) * 8)];
      bfr[n][1] = *(const bf16x8*)&sB[r * 64 + (((u0 + 4) ^ sw) * 8)];
    }
    #pragma unroll
    for (int i = 0; i < 4; i++)
      #pragma unroll
      for (int n = 0; n < 4; n++) {
        acc[i][n] = __builtin_amdgcn_mfma_f32_16x16x32_bf16(af[i][0], bfr[n][0], acc[i][n], 0, 0, 0);
        acc[i][n] = __builtin_amdgcn_mfma_f32_16x16x32_bf16(af[i][1], bfr[n][1], acc[i][n], 0, 0, 0);
      }
    __syncthreads();
  }
}

// ---------------- skip GEMM: bf16 output ----------------
__global__ __launch_bounds__(256) void k_gemm_skip(
    const unsigned short* __restrict__ A, const unsigned short* __restrict__ Bm,
    const float* __restrict__ bias, unsigned short* __restrict__ Cb,
    int M, int N, int K) {
  __shared__ unsigned short sA[128 * 64];
  __shared__ unsigned short sB[128 * 64];
  const int t = threadIdx.x;
  const int w = t >> 6, l = t & 63;
  const int wr = w >> 1, wc = w & 1;
  const int lm = l & 15, u0 = l >> 4;
  const int row0 = blockIdx.y * 128, col0 = blockIdx.x * 128;

  f32x4 acc[4][4] = {};
  gemm_core(A, Bm, sA, sB, row0, col0, K, t, wr, wc, lm, u0, acc);

  const int lg = l >> 4;
  #pragma unroll
  for (int n = 0; n < 4; n++) {
    int col = col0 + wc * 64 + n * 16 + lm;
    float bv = bias[col];
    #pragma unroll
    for (int i = 0; i < 4; i++) {
      int rbase = row0 + wr * 64 + i * 16 + lg * 4;
      #pragma unroll
      for (int j = 0; j < 4; j++)
        Cb[(size_t)(rbase + j) * N + col] = f2bf(acc[i][n][j] + bv);
    }
  }
}

// ---------------- exact top-k selection; sorted lists; zero-fill early + scatter late ----------------
__global__ __launch_bounds__(256) void k_select(
    const u64* __restrict__ cand, const unsigned int* __restrict__ rowcnt,
    const unsigned char* __restrict__ xf8, const unsigned char* __restrict__ wenc8,
    const float* __restrict__ benc,
    float* __restrict__ menc, uint2* __restrict__ lists, unsigned int* __restrict__ l0p) {
  __shared__ u64 sc[CCAP];               // 8 KB
  __shared__ unsigned int hist[NBIN];    // 8 KB
  __shared__ u64 scratch[256];           // 2 KB (aliased as xrow in fallback)
  __shared__ unsigned int sS[256];       // 1 KB
  __shared__ uint2 win[256];             // 2 KB
  __shared__ int s_bb[3];
  __shared__ unsigned int s_bc[3];
  __shared__ u64 s_T[3];
  __shared__ int s_scnt;
  __shared__ unsigned int s_l0, s_pos;

  const int b = blockIdx.x, t = threadIdx.x;
  float* rowp = menc + (size_t)b * L_DIM;

  int cnt = (int)rowcnt[b];
  if (cnt >= 256 && cnt <= CCAP) {
    for (int i = t; i < cnt; i += 256) sc[i] = cand[(size_t)b * CCAP + i];
    // early coalesced zero-fill of menc row: stores drain under the selection compute
    #pragma unroll 4
    for (int g = 0; g < 16; g++) {
      f32x4 z = {};
      *(f32x4*)&rowp[g * 1024 + t * 4] = z;
    }
    __syncthreads();
  } else {
    // ---- fallback (never expected): recompute pre (fp8 x fp8, identity layout) ----
    unsigned char* xrow = (unsigned char*)scratch;     // 1024 bytes
    for (int i = t; i < D_IN; i += 256) xrow[i] = xf8[(size_t)b * D_IN + i];
    __syncthreads();
    for (int q = 0; q < 64; q++) {
      int lat = q * 256 + t;
      const unsigned char* wp = &wenc8[(size_t)lat * D_IN];
      float a = 0.f;
      for (int k = 0; k < D_IN; k++) a += e4m3f(xrow[k]) * e4m3f(wp[k]);
      rowp[lat] = a + benc[lat];           // rowp used as scratch
    }
    __syncthreads();
    float T = 1.7f;
    for (int at = 0; at < 10; at++) {
      if (t == 0) s_scnt = 0;
      __syncthreads();
      int loc = 0;
      for (int q = 0; q < 64; q++) loc += (rowp[q * 256 + t] > T) ? 1 : 0;
      atomicAdd(&s_scnt, loc);
      __syncthreads();
      int c2 = s_scnt;
      if (c2 >= 256 && c2 <= CCAP) break;
      T = (c2 < 256) ? (T - 0.5f) : (T + 0.3f);
      __syncthreads();
    }
    if (t == 0) s_scnt = 0;
    __syncthreads();
    for (int q = 0; q < 64; q++) {
      int lat = q * 256 + t;
      float v = rowp[lat];
      if (v > T) {
        int p = atomicAdd(&s_scnt, 1);
        if (p < CCAP) sc[p] = ((u64)sortkey(v) << 32) | (unsigned int)(~(unsigned int)lat);
      }
    }
    __syncthreads();
    cnt = min(s_scnt, CCAP);
    for (int i = t * 4; i < L_DIM; i += 1024) { f32x4 z = {}; *(f32x4*)&rowp[i] = z; }
    __syncthreads();
  }

  // histogram over candidate values
  for (int i = t; i < NBIN; i += 256) hist[i] = 0u;
  __syncthreads();
  for (int i = t; i < cnt; i += 256) {
    float v = keyval((unsigned int)(sc[i] >> 32));
    atomicAdd(&hist[binof(v)], 1u);
  }
  __syncthreads();

  // suffix counts
  unsigned int csum = 0;
  #pragma unroll
  for (int j = 0; j < 8; j++) csum += hist[t * 8 + j];
  sS[t] = csum;
  __syncthreads();
  for (int off = 1; off < 256; off <<= 1) {
    unsigned int v2 = (t + off < 256) ? sS[t + off] : 0u;
    __syncthreads();
    sS[t] += v2;
    __syncthreads();
  }
  {
    unsigned int above = (t < 255) ? sS[t + 1] : 0u;
    unsigned int run = 0;
    for (int j = 7; j >= 0; j--) {
      int bb = t * 8 + j;
      unsigned int S = above + run, h = hist[bb];
      if (h) {
        if (S < 32u  && 32u  <= S + h) { s_bb[0] = bb; s_bc[0] = S; }
        if (S < 128u && 128u <= S + h) { s_bb[1] = bb; s_bc[1] = S; }
        if (S < 256u && 256u <= S + h) { s_bb[2] = bb; s_bc[2] = S; }
      }
      run += h;
    }
  }
  __syncthreads();

  // resolve exact threshold ukeys inside each boundary bin
  for (int ri = 0; ri < 3; ri++) {
    const int r = (ri == 0) ? 32 : (ri == 1) ? 128 : 256;
    int bb = s_bb[ri];
    int cA = (int)s_bc[ri];
    if (t == 0) s_scnt = 0;
    __syncthreads();
    for (int i = t; i < cnt; i += 256) {
      float v = keyval((unsigned int)(sc[i] >> 32));
      if (binof(v) == bb) {
        int p = atomicAdd(&s_scnt, 1);
        if (p < 256) scratch[p] = sc[i];
      }
    }
    __syncthreads();
    int m = min(s_scnt, 256);
    for (int i = t; i < m; i += 256) {
      u64 me = scratch[i];
      int rk = 0;
      for (int j2 = 0; j2 < m; j2++) rk += (scratch[j2] > me) ? 1 : 0;
      if (rk == r - cA - 1) s_T[ri] = me;
    }
    __syncthreads();
  }

  // classify candidates, collect winners into win[]
  if (t == 0) { s_pos = 0u; s_l0 = 0u; }
  __syncthreads();
  const u64 T32 = s_T[0], T128 = s_T[1], T256 = s_T[2];
  for (int i = t; i < cnt; i += 256) {
    u64 e = sc[i];
    int w = (e >= T32) ? 3 : (e >= T128) ? 2 : (e >= T256) ? 1 : 0;
    if (w) {
      unsigned int p = atomicAdd(&s_pos, 1u);
      int idx = (int)(~(unsigned int)e) & (L_DIM - 1);
      float v = keyval((unsigned int)(e >> 32));
      float rv = fmaxf(v, 0.f);
      if (p < 256u)
        win[p] = make_uint2((unsigned int)idx | ((unsigned int)w << 20), __float_as_uint(rv));
      if (rv > 0.f) atomicAdd(&s_l0, 1u);
    }
  }
  __syncthreads();
  // pad (sorts last; weight bits decode to 0 -> scatter writes 0, harmless)
  for (int i = (int)s_pos + t; i < 256; i += 256) win[i] = make_uint2(0xFFFFFu, 0u);
  __syncthreads();

  // bitonic sort win[] ascending by latent idx
  for (int k = 2; k <= 256; k <<= 1) {
    for (int j = k >> 1; j > 0; j >>= 1) {
      int x = t ^ j;
      if (x > t) {
        uint2 a = win[t], bb2 = win[x];
        bool asc = ((t & k) == 0);
        bool swap = asc ? ((a.x & 0xFFFFFu) > (bb2.x & 0xFFFFFu))
                        : ((a.x & 0xFFFFFu) < (bb2.x & 0xFFFFFu));
        if (swap) { win[t] = bb2; win[x] = a; }
      }
      __syncthreads();
    }
  }

  lists[(size_t)b * 256 + t] = win[t];

  // scatter winners over the (already drained) zeroed row: one 4B store per thread
  {
    uint2 e = win[t];
    int idx = (int)(e.x & 0xFFFFFu) & (L_DIM - 1);
    unsigned int wg = (e.x >> 20) & 3u;
    float rv = __uint_as_float(e.y);
    rowp[idx] = rv * (float)wg * (1.f / 3.f);
  }

  if (t == 0) atomicAdd(l0p, s_l0);
}

// ---------------- sparse decode: int8 W_dec gather, 512 thr, 4 groups ----------------
// r6-proven structure (depth-8): 8 independent gathers in flight + scalar row base via
// readfirstlane. Depth-16 (r7) regressed: VGPR >100 dropped occupancy 32->20 waves/CU,
// which outweighed added per-wave depth for this latency-bound gather. Keep depth 8.
#define DEC_PROC(E, Q)                                             \
  do {                                                             \
    int wgt_ = (int)(((E).x >> 20) & 3u);                          \
    float v_ = __uint_as_float((E).y) * (1.0f / W8SCALE);          \
    float f_[8];                                                   \
    _Pragma("unroll")                                              \
    for (int j_ = 0; j_ < 4; j_++) {                               \
      f_[j_]     = (float)((int)((Q).x << (24 - 8 * j_)) >> 24);   \
      f_[4 + j_] = (float)((int)((Q).y << (24 - 8 * j_)) >> 24);   \
    }                                                              \
    if (wgt_ == 3) {                                               \
      _Pragma("unroll")                                            \
      for (int j_ = 0; j_ < 8; j_++) a1[j_] += v_ * f_[j_];        \
    } else if (wgt_ == 2) {                                        \
      _Pragma("unroll")                                            \
      for (int j_ = 0; j_ < 8; j_++) a2[j_] += v_ * f_[j_];        \
    } else {                                                       \
      _Pragma("unroll")                                            \
      for (int j_ = 0; j_ < 8; j_++) a3[j_] += v_ * f_[j_];        \
    }                                                              \
  } while (0)

__global__ __launch_bounds__(512) void k_decode(
    const uint2* __restrict__ lists, const unsigned char* __restrict__ W8,
    const unsigned short* __restrict__ skipb, const float* __restrict__ mlp,
    float* __restrict__ mdec, float* __restrict__ loss_acc) {
  __shared__ uint2 ll[256];
  __shared__ float part[3][24][128];   // [group-1][class*8+col][lane] - stride-1 in lane
  __shared__ float red[2];
  const int b = blockIdx.x, t = threadIdx.x;
  if (t < 256) ll[t] = lists[(size_t)b * 256 + t];
  __syncthreads();

  const int lane = t & 127, grp = t >> 7;   // 4 groups x 128 lanes
  const int c = lane * 8;                   // loop-invariant voffset (bytes)

  float a1[8] = {}, a2[8] = {}, a3[8] = {};

  // group grp processes sorted entries 4i+grp; batches of 8 independent gathers
  for (int i0 = 0; i0 < 64; i0 += 8) {
    uint2 e0 = ll[4 * (i0 + 0) + grp];
    uint2 e1 = ll[4 * (i0 + 1) + grp];
    uint2 e2 = ll[4 * (i0 + 2) + grp];
    uint2 e3 = ll[4 * (i0 + 3) + grp];
    uint2 e4 = ll[4 * (i0 + 4) + grp];
    uint2 e5 = ll[4 * (i0 + 5) + grp];
    uint2 e6 = ll[4 * (i0 + 6) + grp];
    uint2 e7 = ll[4 * (i0 + 7) + grp];
    // scalar row bases (entry index is uniform across the group's waves)
    const unsigned char* r0p = W8 + (size_t)((unsigned)__builtin_amdgcn_readfirstlane(e0.x) & (L_DIM - 1)) * D_IN;
    const unsigned char* r1p = W8 + (size_t)((unsigned)__builtin_amdgcn_readfirstlane(e1.x) & (L_DIM - 1)) * D_IN;
    const unsigned char* r2p = W8 + (size_t)((unsigned)__builtin_amdgcn_readfirstlane(e2.x) & (L_DIM - 1)) * D_IN;
    const unsigned char* r3p = W8 + (size_t)((unsigned)__builtin_amdgcn_readfirstlane(e3.x) & (L_DIM - 1)) * D_IN;
    const unsigned char* r4p = W8 + (size_t)((unsigned)__builtin_amdgcn_readfirstlane(e4.x) & (L_DIM - 1)) * D_IN;
    const unsigned char* r5p = W8 + (size_t)((unsigned)__builtin_amdgcn_readfirstlane(e5.x) & (L_DIM - 1)) * D_IN;
    const unsigned char* r6p = W8 + (size_t)((unsigned)__builtin_amdgcn_readfirstlane(e6.x) & (L_DIM - 1)) * D_IN;
    const unsigned char* r7p = W8 + (size_t)((unsigned)__builtin_amdgcn_readfirstlane(e7.x) & (L_DIM - 1)) * D_IN;
    // 8 independent gathers in flight
    uint2 q0 = *(const uint2*)(r0p + c);
    uint2 q1 = *(const uint2*)(r1p + c);
    uint2 q2 = *(const uint2*)(r2p + c);
    uint2 q3 = *(const uint2*)(r3p + c);
    uint2 q4 = *(const uint2*)(r4p + c);
    uint2 q5 = *(const uint2*)(r5p + c);
    uint2 q6 = *(const uint2*)(r6p + c);
    uint2 q7 = *(const uint2*)(r7p + c);
    DEC_PROC(e0, q0);
    DEC_PROC(e1, q1);
    DEC_PROC(e2, q2);
    DEC_PROC(e3, q3);
    DEC_PROC(e4, q4);
    DEC_PROC(e5, q5);
    DEC_PROC(e6, q6);
    DEC_PROC(e7, q7);
  }

  if (grp != 0) {
    #pragma unroll
    for (int j = 0; j < 8; j++) {
      part[grp - 1][j][lane]      = a1[j];
      part[grp - 1][8 + j][lane]  = a2[j];
      part[grp - 1][16 + j][lane] = a3[j];
    }
  }
  __syncthreads();

  float lsum = 0.f;
  if (grp == 0) {
    #pragma unroll
    for (int g = 0; g < 3; g++) {
      #pragma unroll
      for (int j = 0; j < 8; j++) {
        a1[j] += part[g][j][lane];
        a2[j] += part[g][8 + j][lane];
        a3[j] += part[g][16 + j][lane];
      }
    }
    u16x8 skv = *(const u16x8*)&skipb[(size_t)b * D_IN + c];
    f32x4 m0 = *(const f32x4*)&mlp[(size_t)b * D_IN + c];
    f32x4 m1 = *(const f32x4*)&mlp[(size_t)b * D_IN + c + 4];
    float mm[8] = {m0[0], m0[1], m0[2], m0[3], m1[0], m1[1], m1[2], m1[3]};
    float md[8];
    #pragma unroll
    for (int j = 0; j < 8; j++) {
      float sk   = bf2f(skv[j]);
      float d32  = sk + a1[j];
      float d128 = d32 + a2[j];
      float d256 = d128 + a3[j];
      md[j] = (d32 + d128 + d256) * (1.f / 3.f);
      float e1 = mm[j] - d32, e2 = mm[j] - d128, e3 = mm[j] - d256;
      lsum += e1 * e1 + e2 * e2 + e3 * e3;
    }
    f32x4 o0 = {md[0], md[1], md[2], md[3]};
    f32x4 o1 = {md[4], md[5], md[6], md[7]};
    *(f32x4*)&mdec[(size_t)b * D_IN + c]     = o0;
    *(f32x4*)&mdec[(size_t)b * D_IN + c + 4] = o1;
  }

  lsum = waveSum(lsum);                 // waves 2..7 sum to 0
  if ((t & 63) == 0 && t < 128) red[t >> 6] = lsum;
  __syncthreads();
  if (t == 0) atomicAdd(loss_acc, red[0] + red[1]);
}

// ---------------- finalize scalars ----------------
__global__ void k_final(const float* scal, const unsigned int* l0p, float* outscal) {
  outscal[0] = scal[0] / scal[1];
  outscal[1] = (float)(*l0p);
}

// ---------------- host launch ----------------
extern "C" void kernel_launch(void* const* d_in, const int* in_sizes, int n_in,
                              void* d_out, int out_size, void* d_ws, size_t ws_size,
                              hipStream_t stream) {
  (void)in_sizes; (void)n_in; (void)out_size; (void)ws_size;
  const float* x     = (const float*)d_in[0];
  const float* mlp   = (const float*)d_in[1];
  const float* Wenc  = (const float*)d_in[2];
  const float* benc  = (const float*)d_in[3];
  const float* Wdec  = (const float*)d_in[4];
  const float* bdec  = (const float*)d_in[5];
  const float* Wskip = (const float*)d_in[6];

  char* ws = (char*)d_ws;
  float*          scal    = (float*)(ws + 0);                 // [0]=loss [1]=var
  unsigned int*   l0p     = (unsigned int*)(ws + 8);
  float*          colsum  = (float*)(ws + 256);
  float*          colsq   = (float*)(ws + 4352);
  unsigned int*   rowcnt  = (unsigned int*)(ws + 8448);        // 16 KB
  unsigned short* xb      = (unsigned short*)(ws + 24832);     // 8 MB (bf16, for skip GEMM)
  unsigned char*  wenc8   = (unsigned char*)(ws + 8413440);    // 16 MB (fp8 W_enc, identity)
  unsigned char*  xf8     = (unsigned char*)(ws + 8413440 + 16777216);  // 4 MB (fp8 x, identity)
  unsigned short* wsktb   = (unsigned short*)(ws + 41967872);  // 2 MB
  unsigned short* skipb   = (unsigned short*)(ws + 44065024);  // 8 MB (bf16)
  uint2*          lists   = (uint2*)(ws + 52453632);           // 8 MB
  u64*            cand    = (u64*)(ws + 60842240);             // 32 MB
  unsigned char*  wdec8   = (unsigned char*)(ws + 60842240);   // 16 MB, aliases cand (after select)

  float* out  = (float*)d_out;
  float* menc = out;
  float* mdec = out + (size_t)B_ROWS * L_DIM;
  float* oscl = out + (size_t)B_ROWS * L_DIM + (size_t)B_ROWS * D_IN;

  k_prep<<<2048, 256, 0, stream>>>(x, xb, xf8, scal, colsum, colsq, rowcnt, (B_ROWS * D_IN) / 4);
  k_convert_fp8<<<2048, 256, 0, stream>>>(Wenc, wenc8, (L_DIM * D_IN) / 4);
  k_transpose_bf<<<dim3(32, 32), dim3(32, 32), 0, stream>>>(Wskip, wsktb, D_IN);
  k_var1<<<128, 256, 0, stream>>>(x, colsum, colsq);
  k_var2<<<1, 256, 0, stream>>>(colsum, colsq, scal);
  k_gemm_enc<<<dim3(L_DIM / 128, B_ROWS / 128), 256, 0, stream>>>(
      xf8, wenc8, benc, cand, rowcnt, B_ROWS, L_DIM, D_IN);
  k_gemm_skip<<<dim3(D_IN / 128, B_ROWS / 128), 256, 0, stream>>>(
      xb, wsktb, bdec, skipb, B_ROWS, D_IN, D_IN);
  k_select<<<B_ROWS, 256, 0, stream>>>(cand, rowcnt, xf8, wenc8, benc, menc, lists, l0p);
  k_convert_i8<<<2048, 256, 0, stream>>>(Wdec, (unsigned int*)wdec8, (L_DIM * D_IN) / 4);  // aliases cand
  k_decode<<<B_ROWS, 512, 0, stream>>>(lists, wdec8, skipb, mlp, mdec, scal);
  k_final<<<1, 1, 0, stream>>>(scal, l0p, oscl);
}

// Round 9
// 448.490 us; speedup vs baseline: 1.0587x; 1.0187x over previous
//
#include <hip/hip_runtime.h>
#include <stdint.h>

// ---------------- types ----------------
typedef short   bf16x8 __attribute__((ext_vector_type(8)));
typedef float   f32x4  __attribute__((ext_vector_type(4)));
typedef float   f32x16 __attribute__((ext_vector_type(16)));
typedef int     i32x4  __attribute__((ext_vector_type(4)));
typedef int     i32x8  __attribute__((ext_vector_type(8)));
typedef unsigned short u16x8 __attribute__((ext_vector_type(8)));
typedef unsigned long long u64;
typedef long long i64;
typedef long long i64x2 __attribute__((ext_vector_type(2)));

#define B_ROWS 4096
#define D_IN   1024
#define L_DIM  16384
#define NBIN   2048
#define CCAP   1024
#define SLOTS  32
#define W8SCALE 1200.0f

// ---------------- helpers ----------------
__device__ __forceinline__ unsigned short f2bf(float f) {
  unsigned int u = __float_as_uint(f);
  u = (u + 0x7FFFu + ((u >> 16) & 1u)) >> 16;   // RNE to bf16
  return (unsigned short)u;
}
__device__ __forceinline__ float bf2f(unsigned short h) {
  return __uint_as_float(((unsigned int)h) << 16);
}
// f32 -> OCP e4m3fn (RNE, flush exp<=0 to 0, clamp 448)
__device__ __forceinline__ unsigned char f2e4m3(float v) {
  unsigned int u = __float_as_uint(v);
  unsigned int s = (u >> 24) & 0x80u;
  unsigned int a = u & 0x7FFFFFFFu;
  unsigned int r = (a + 0x0007FFFFu + ((a >> 20) & 1u)) >> 20;   // (exp<<3)|man, rounded
  if (r <= (120u << 3)) return (unsigned char)s;                 // underflow -> +-0
  r -= (120u << 3);
  if (r > 0x7Eu) r = 0x7Eu;                                      // clamp to 448
  return (unsigned char)(s | r);
}
__device__ __forceinline__ float e4m3f(unsigned char b) {
  unsigned int e = (b >> 3) & 0xFu, m = b & 7u, s = ((unsigned int)b & 0x80u) << 24;
  if (e == 0) return __uint_as_float(s);
  return __uint_as_float(s | ((e + 120u) << 23) | (m << 20));
}
__device__ __forceinline__ unsigned int sortkey(float f) {
  unsigned int u = __float_as_uint(f);
  return (u & 0x80000000u) ? ~u : (u | 0x80000000u);
}
__device__ __forceinline__ float keyval(unsigned int k) {
  unsigned int u = (k & 0x80000000u) ? (k & 0x7FFFFFFFu) : ~k;
  return __uint_as_float(u);
}
__device__ __forceinline__ int binof(float v) {
  int b = (int)((v + 2.0f) * (2048.0f / 7.0f));
  return b < 0 ? 0 : (b > 2047 ? 2047 : b);
}
__device__ __forceinline__ void gl_lds16(const void* g, void* l) {
  __builtin_amdgcn_global_load_lds(
      (const __attribute__((address_space(1))) unsigned int*)g,
      (__attribute__((address_space(3))) unsigned int*)l, 16, 0, 0);
}
__device__ __forceinline__ float waveSum(float v) {
  #pragma unroll
  for (int m = 32; m; m >>= 1) v += __shfl_xor(v, m);
  return v;
}

// ---------------- fused prep: zero bookkeeping + x -> bf16 + x -> fp8 (one x pass) ----------
__global__ void k_prep(const float* __restrict__ x,
                       unsigned short* __restrict__ xb, unsigned char* __restrict__ xf8,
                       float* scal, float* colsum, float* colsq, unsigned int* rowcnt,
                       int n4) {
  int gt = blockIdx.x * blockDim.x + threadIdx.x;
  if (gt < 8) scal[gt] = 0.f;              // [0]=loss, [1]=var
  if (gt < 1024) { colsum[gt] = 0.f; colsq[gt] = 0.f; }
  if (gt < B_ROWS) rowcnt[gt] = 0u;
  int stride = gridDim.x * blockDim.x;
  for (int i = gt; i < n4; i += stride) {
    f32x4 v = *((const f32x4*)x + i);
    ushort4 o;
    o.x = f2bf(v[0]); o.y = f2bf(v[1]); o.z = f2bf(v[2]); o.w = f2bf(v[3]);
    *((ushort4*)xb + i) = o;
    unsigned int u = 0;
    #pragma unroll
    for (int j = 0; j < 4; j++) u |= ((unsigned int)f2e4m3(v[j])) << (8 * j);
    *((unsigned int*)xf8 + i) = u;
  }
}

// ---------------- convert f32 -> fp8 e4m3, IDENTITY layout (W_enc) ----------------
__global__ void k_convert_fp8(const float* __restrict__ in, unsigned char* __restrict__ out, int n4) {
  int i = blockIdx.x * blockDim.x + threadIdx.x;
  int stride = gridDim.x * blockDim.x;
  for (; i < n4; i += stride) {
    f32x4 v = *((const f32x4*)in + i);
    unsigned int u = 0;
    #pragma unroll
    for (int j = 0; j < 4; j++) u |= ((unsigned int)f2e4m3(v[j])) << (8 * j);
    *((unsigned int*)out + i) = u;
  }
}

// ---------------- convert f32 -> int8 (scale W8SCALE, clamp +-127), packed 4/word ----------------
__global__ void k_convert_i8(const float* __restrict__ in, unsigned int* __restrict__ out, int n4) {
  int i = blockIdx.x * blockDim.x + threadIdx.x;
  int stride = gridDim.x * blockDim.x;
  for (; i < n4; i += stride) {
    f32x4 v = *((const f32x4*)in + i);
    unsigned int u = 0;
    #pragma unroll
    for (int j = 0; j < 4; j++) {
      int q = (int)rintf(v[j] * W8SCALE);
      q = q > 127 ? 127 : (q < -127 ? -127 : q);
      u |= ((unsigned int)q & 0xFFu) << (8 * j);
    }
    out[i] = u;
  }
}

// ---------------- transpose W_skip (f32 in) -> bf16 out, out[c][r]=in[r][c] ----------------
__global__ void k_transpose_bf(const float* __restrict__ in, unsigned short* __restrict__ out, int n) {
  __shared__ float tile[32][33];
  int bx = blockIdx.x * 32, by = blockIdx.y * 32;
  int tx = threadIdx.x, ty = threadIdx.y;
  tile[ty][tx] = in[(size_t)(by + ty) * n + bx + tx];
  __syncthreads();
  out[(size_t)(bx + ty) * n + by + tx] = f2bf(tile[tx][ty]);
}

// ---------------- variance pass 1 ----------------
__global__ __launch_bounds__(256) void k_var1(const float* __restrict__ x, float* colsum, float* colsq) {
  int g = blockIdx.x;
  int t = threadIdx.x;
  float s[4] = {0,0,0,0}, q[4] = {0,0,0,0};
  for (int r = 0; r < 32; r++) {
    const float* rp = x + (size_t)(g * 32 + r) * D_IN;
    #pragma unroll
    for (int j = 0; j < 4; j++) {
      float v = rp[t + 256 * j];
      s[j] += v; q[j] += v * v;
    }
  }
  #pragma unroll
  for (int j = 0; j < 4; j++) {
    atomicAdd(&colsum[t + 256 * j], s[j]);
    atomicAdd(&colsq [t + 256 * j], q[j]);
  }
}

// ---------------- variance pass 2 ----------------
__global__ __launch_bounds__(256) void k_var2(const float* colsum, const float* colsq, float* scal) {
  __shared__ float red[4];
  int t = threadIdx.x;
  float loc = 0.f;
  #pragma unroll
  for (int j = 0; j < 4; j++) {
    int c = t + 256 * j;
    float cs = colsum[c], cq = colsq[c];
    loc += cq - cs * cs * (1.f / (float)B_ROWS);
  }
  loc = waveSum(loc);
  if ((t & 63) == 0) red[t >> 6] = loc;
  __syncthreads();
  if (t == 0) scal[1] = red[0] + red[1] + red[2] + red[3];
}

// =================================================================================
// 128x128-tile, 256-thread (4-wave), triple-buffered FP8 encoder GEMM, BK=64.
// MX-scaled path: mfma_scale_f32_32x32x64_f8f6f4 with unit scales (E8M0 0x7F = 1.0).
// =================================================================================
__device__ __forceinline__ void stage_half8(const unsigned char* __restrict__ G,
                                            int Kb, int r0, int k0b,
                                            unsigned char* buf, int t) {
  #pragma unroll
  for (int j = 0; j < 2; j++) {
    int q = j * 256 + t;                // 512 x 16B = 8KB (128 rows x 64B)
    int row = q >> 2, u = q & 3;
    int uu = u ^ ((row >> 1) & 3);
    gl_lds16(&G[(size_t)(r0 + row) * Kb + k0b + uu * 16], &buf[q * 16]);
  }
}

__global__ __launch_bounds__(256, 3) void k_gemm_enc(
    const unsigned char* __restrict__ A8, const unsigned char* __restrict__ B8,
    const float* __restrict__ bias,
    u64* __restrict__ cand, unsigned int* __restrict__ rowcnt,
    int M, int N, int K) {
  __shared__ unsigned char sBuf[3 * 16384];     // 48 KB
  // epilogue aliases (used only after full drain + __syncthreads):
  unsigned int*  stageKey = (unsigned int*)sBuf;                 // 16 KB (128*32 u32)
  unsigned char* stageCol = (unsigned char*)&sBuf[16384];        // 4 KB
  unsigned int*  s_cnt    = (unsigned int*)&sBuf[20480];         // 512 B (128)
  unsigned int*  s_base   = (unsigned int*)&sBuf[21504];         // 512 B (128)

  const int t = threadIdx.x;
  const int w = t >> 6, l = t & 63;
  const int wr = w >> 1, wc = w & 1;           // 2x2 wave grid, wave tile 64x64
  const int lr = l & 31, lh = l >> 5;          // fragment row-in-32, K-half
  const int row0 = blockIdx.y * 128, col0 = blockIdx.x * 128;
  const int Kb = K;                             // bytes per row (fp8)
  const int NT = K >> 6;                        // 16 K-tiles of BK=64

  f32x16 acc[2][2] = {};                        // 2x2 of 32x32 tiles = 64x64/wave

  // prologue: K-tiles 0,1 staged (4 half-stages = 8 loads/thread)
  stage_half8(A8, Kb, row0, 0,   sBuf + 0,             t);
  stage_half8(B8, Kb, col0, 0,   sBuf + 8192,          t);
  stage_half8(A8, Kb, row0, 64,  sBuf + 16384,         t);
  stage_half8(B8, Kb, col0, 64,  sBuf + 16384 + 8192,  t);

  // per-lane fragment byte offsets, hoisted out of the loop.
  const int raf = wr * 64 + lr,  swa = (raf >> 1) & 3;
  const int rbf = wc * 64 + lr,  swb = (rbf >> 1) & 3;
  const int uA0 = ((2 * lh)     ^ swa) * 16, uA1 = ((2 * lh + 1) ^ swa) * 16;
  const int uB0 = ((2 * lh)     ^ swb) * 16, uB1 = ((2 * lh + 1) ^ swb) * 16;
  const int offA0 = raf * 64,        offA1 = (raf + 32) * 64;
  const int offB0 = 8192 + rbf * 64, offB1 = 8192 + (rbf + 32) * 64;

  for (int tt = 0; tt < NT; tt++) {
    asm volatile("s_waitcnt vmcnt(4)" ::: "memory");   // tile tt landed; tt+1 in flight
    __builtin_amdgcn_s_barrier();

    int ks = (tt + 2 < NT) ? (tt + 2) : (NT - 1);      // dummy tail restage keeps vmcnt uniform
    unsigned char* nb = sBuf + ((tt + 2) % 3) * 16384;
    stage_half8(A8, Kb, row0, ks * 64, nb, t);
    stage_half8(B8, Kb, col0, ks * 64, nb + 8192, t);

    const unsigned char* cb = sBuf + (tt % 3) * 16384;

    // fragment reads: two ds_read_b128 per 32-row block (lane's 32 contiguous K-bytes)
    union Frag { i32x8 w; i32x4 h[2]; };
    Frag av[2], bv[2];
    av[0].h[0] = *(const i32x4*)&cb[offA0 + uA0];
    av[0].h[1] = *(const i32x4*)&cb[offA0 + uA1];
    av[1].h[0] = *(const i32x4*)&cb[offA1 + uA0];
    av[1].h[1] = *(const i32x4*)&cb[offA1 + uA1];
    bv[0].h[0] = *(const i32x4*)&cb[offB0 + uB0];
    bv[0].h[1] = *(const i32x4*)&cb[offB0 + uB1];
    bv[1].h[0] = *(const i32x4*)&cb[offB1 + uB0];
    bv[1].h[1] = *(const i32x4*)&cb[offB1 + uB1];

    __builtin_amdgcn_s_setprio(1);
    #pragma unroll
    for (int mt = 0; mt < 2; mt++)
      #pragma unroll
      for (int nt = 0; nt < 2; nt++)
        acc[mt][nt] = __builtin_amdgcn_mfma_scale_f32_32x32x64_f8f6f4(
            av[mt].w, bv[nt].w, acc[mt][nt],
            0, 0,                   // cbsz=fp8(e4m3), blgp=fp8(e4m3)
            0, 0x7F7F7F7Fu,         // A scale: byte0, E8M0 127 = 1.0
            0, 0x7F7F7F7Fu);        // B scale: byte0, E8M0 127 = 1.0
    __builtin_amdgcn_s_setprio(0);
  }

  // full drain before reusing LDS for the epilogue stage
  asm volatile("s_waitcnt vmcnt(0) lgkmcnt(0)" ::: "memory");
  __syncthreads();

  if (t < 128) s_cnt[t] = 0u;
  __syncthreads();

  // scan 64 values/thread into LDS stage (cheap LDS atomics only)
  // 32x32 C/D layout: col = lane&31, row = (reg&3) + 8*(reg>>2) + 4*(lane>>5)
  #pragma unroll
  for (int nt = 0; nt < 2; nt++) {
    int cl = wc * 64 + nt * 32 + lr;           // local col 0..127
    float bvs = bias[col0 + cl];
    #pragma unroll
    for (int mt = 0; mt < 2; mt++) {
      int rbase = wr * 64 + mt * 32 + lh * 4;
      #pragma unroll
      for (int i = 0; i < 16; i++) {
        float v = acc[mt][nt][i] + bvs;
        if (v > 1.7f) {
          int r = rbase + (i & 3) + 8 * (i >> 2);
          unsigned int p = atomicAdd(&s_cnt[r], 1u);
          if (p < SLOTS) {
            stageKey[r * SLOTS + p] = sortkey(v);
            stageCol[r * SLOTS + p] = (unsigned char)cl;
          }
        }
      }
    }
  }
  __syncthreads();

  // one global atomic per (block,row): reserve space (poison on overflow)
  if (t < 128) {
    unsigned int c = s_cnt[t];
    if (c > SLOTS)      { atomicAdd(&rowcnt[row0 + t], 4096u); s_base[t] = 0x80000000u; }
    else if (c)         s_base[t] = atomicAdd(&rowcnt[row0 + t], c);
    else                s_base[t] = 0u;
  }
  __syncthreads();

  // batched copy-out of staged candidates
  for (int s = t; s < 128 * SLOTS; s += 256) {
    int r = s >> 5, p = s & (SLOTS - 1);
    unsigned int c = s_cnt[r], g0 = s_base[r];
    if ((unsigned int)p < c && c <= SLOTS && !(g0 & 0x80000000u)) {
      unsigned int g = g0 + (unsigned int)p;
      if (g < CCAP)
        cand[(size_t)(row0 + r) * CCAP + g] =
            ((u64)stageKey[s] << 32) | (unsigned int)(~(unsigned int)(col0 + stageCol[s]));
    }
  }
}

// ---------------- skip GEMM staging (BK=64, XOR-swizzled), 4x gl_lds16/thread/matrix ------
__device__ __forceinline__ void stage_swz(const unsigned short* __restrict__ G, int ld,
                                          int r0, int k0, unsigned short* lds, int t) {
  #pragma unroll
  for (int j = 0; j < 4; j++) {
    int q = j * 256 + t;
    int row = q >> 3, u = q & 7;
    int uu = u ^ (row & 7);
    gl_lds16(&G[(size_t)(r0 + row) * ld + k0 + uu * 8], &lds[q * 8]);
  }
}

// ---------------- skip GEMM: bf16, 128x128 tile, TRIPLE-BUFFERED vmcnt(8) schedule -------
// r9 change: port k_gemm_enc's proven prefetch schedule (prologue stages tiles 0,1;
// per-iter vmcnt(8) -> barrier -> stage(t+2) -> frag reads -> MFMA; dummy tail restage).
// Old version was single-buffered with 2 full barriers/K-step at 1 block/CU (grid=256)
// and 4 waves/CU - nothing hid the stage latency. LDS 32->96 KB is free (grid-limited).
// Identical fragment layout + MFMA order -> bit-identical output.
__global__ __launch_bounds__(256) void k_gemm_skip(
    const unsigned short* __restrict__ A, const unsigned short* __restrict__ Bm,
    const float* __restrict__ bias, unsigned short* __restrict__ Cb,
    int M, int N, int K) {
  __shared__ unsigned short sBuf[3 * 16384];    // 3 bufs x (A 8192 + B 8192 shorts) = 96 KB
  const int t = threadIdx.x;
  const int w = t >> 6, l = t & 63;
  const int wr = w >> 1, wc = w & 1;
  const int lm = l & 15, u0 = l >> 4;
  const int row0 = blockIdx.y * 128, col0 = blockIdx.x * 128;
  const int NT = K >> 6;                        // 16 K-tiles

  f32x4 acc[4][4] = {};

  // prologue: stage tiles 0 and 1 (8 loads/thread each tile)
  stage_swz(A,  K, row0, 0,  sBuf + 0,            t);
  stage_swz(Bm, K, col0, 0,  sBuf + 8192,         t);
  stage_swz(A,  K, row0, 64, sBuf + 16384,        t);
  stage_swz(Bm, K, col0, 64, sBuf + 16384 + 8192, t);

  for (int tt = 0; tt < NT; tt++) {
    asm volatile("s_waitcnt vmcnt(8)" ::: "memory");   // tile tt landed; tt+1 in flight
    __builtin_amdgcn_s_barrier();

    int ks = (tt + 2 < NT) ? (tt + 2) : (NT - 1);      // dummy tail restage keeps counts uniform
    unsigned short* nb = sBuf + ((tt + 2) % 3) * 16384;
    stage_swz(A,  K, row0, ks * 64, nb, t);
    stage_swz(Bm, K, col0, ks * 64, nb + 8192, t);

    const unsigned short* sA = sBuf + (tt % 3) * 16384;
    const unsigned short* sB = sA + 8192;

    bf16x8 af[4][2], bfr[4][2];
    #pragma unroll
    for (int i = 0; i < 4; i++) {
      int r = wr * 64 + i * 16 + lm;
      int sw = r & 7;
      af[i][0] = *(const bf16x8*)&sA[r * 64 + ((u0 ^ sw) * 8)];
      af[i][1] = *(const bf16x8*)&sA[r * 64 + (((u0 + 4) ^ sw) * 8)];
    }
    #pragma unroll
    for (int n = 0; n < 4; n++) {
      int r = wc * 64 + n * 16 + lm;
      int sw = r & 7;
      bfr[n][0] = *(const bf16x8*)&sB[r * 64 + ((u0 ^ sw) * 8)];
      bfr[n][1] = *(const bf16x8*)&sB[r * 64 + (((u0 + 4) ^ sw) * 8)];
    }
    __builtin_amdgcn_s_setprio(1);
    #pragma unroll
    for (int i = 0; i < 4; i++)
      #pragma unroll
      for (int n = 0; n < 4; n++) {
        acc[i][n] = __builtin_amdgcn_mfma_f32_16x16x32_bf16(af[i][0], bfr[n][0], acc[i][n], 0, 0, 0);
        acc[i][n] = __builtin_amdgcn_mfma_f32_16x16x32_bf16(af[i][1], bfr[n][1], acc[i][n], 0, 0, 0);
      }
    __builtin_amdgcn_s_setprio(0);
  }

  // drain outstanding (dummy) stages before exit
  asm volatile("s_waitcnt vmcnt(0) lgkmcnt(0)" ::: "memory");

  const int lg = l >> 4;
  #pragma unroll
  for (int n = 0; n < 4; n++) {
    int col = col0 + wc * 64 + n * 16 + lm;
    float bv = bias[col];
    #pragma unroll
    for (int i = 0; i < 4; i++) {
      int rbase = row0 + wr * 64 + i * 16 + lg * 4;
      #pragma unroll
      for (int j = 0; j < 4; j++)
        Cb[(size_t)(rbase + j) * N + col] = f2bf(acc[i][n][j] + bv);
    }
  }
}

// ---------------- exact top-k selection; sorted lists; zero-fill early + scatter late ----------------
__global__ __launch_bounds__(256) void k_select(
    const u64* __restrict__ cand, const unsigned int* __restrict__ rowcnt,
    const unsigned char* __restrict__ xf8, const unsigned char* __restrict__ wenc8,
    const float* __restrict__ benc,
    float* __restrict__ menc, uint2* __restrict__ lists, unsigned int* __restrict__ l0p) {
  __shared__ u64 sc[CCAP];               // 8 KB
  __shared__ unsigned int hist[NBIN];    // 8 KB
  __shared__ u64 scratch[256];           // 2 KB (aliased as xrow in fallback)
  __shared__ unsigned int sS[256];       // 1 KB
  __shared__ uint2 win[256];             // 2 KB
  __shared__ int s_bb[3];
  __shared__ unsigned int s_bc[3];
  __shared__ u64 s_T[3];
  __shared__ int s_scnt;
  __shared__ unsigned int s_l0, s_pos;

  const int b = blockIdx.x, t = threadIdx.x;
  float* rowp = menc + (size_t)b * L_DIM;

  int cnt = (int)rowcnt[b];
  if (cnt >= 256 && cnt <= CCAP) {
    for (int i = t; i < cnt; i += 256) sc[i] = cand[(size_t)b * CCAP + i];
    // early coalesced zero-fill of menc row: stores drain under the selection compute
    #pragma unroll 4
    for (int g = 0; g < 16; g++) {
      f32x4 z = {};
      *(f32x4*)&rowp[g * 1024 + t * 4] = z;
    }
    __syncthreads();
  } else {
    // ---- fallback (never expected): recompute pre (fp8 x fp8, identity layout) ----
    unsigned char* xrow = (unsigned char*)scratch;     // 1024 bytes
    for (int i = t; i < D_IN; i += 256) xrow[i] = xf8[(size_t)b * D_IN + i];
    __syncthreads();
    for (int q = 0; q < 64; q++) {
      int lat = q * 256 + t;
      const unsigned char* wp = &wenc8[(size_t)lat * D_IN];
      float a = 0.f;
      for (int k = 0; k < D_IN; k++) a += e4m3f(xrow[k]) * e4m3f(wp[k]);
      rowp[lat] = a + benc[lat];           // rowp used as scratch
    }
    __syncthreads();
    float T = 1.7f;
    for (int at = 0; at < 10; at++) {
      if (t == 0) s_scnt = 0;
      __syncthreads();
      int loc = 0;
      for (int q = 0; q < 64; q++) loc += (rowp[q * 256 + t] > T) ? 1 : 0;
      atomicAdd(&s_scnt, loc);
      __syncthreads();
      int c2 = s_scnt;
      if (c2 >= 256 && c2 <= CCAP) break;
      T = (c2 < 256) ? (T - 0.5f) : (T + 0.3f);
      __syncthreads();
    }
    if (t == 0) s_scnt = 0;
    __syncthreads();
    for (int q = 0; q < 64; q++) {
      int lat = q * 256 + t;
      float v = rowp[lat];
      if (v > T) {
        int p = atomicAdd(&s_scnt, 1);
        if (p < CCAP) sc[p] = ((u64)sortkey(v) << 32) | (unsigned int)(~(unsigned int)lat);
      }
    }
    __syncthreads();
    cnt = min(s_scnt, CCAP);
    for (int i = t * 4; i < L_DIM; i += 1024) { f32x4 z = {}; *(f32x4*)&rowp[i] = z; }
    __syncthreads();
  }

  // histogram over candidate values
  for (int i = t; i < NBIN; i += 256) hist[i] = 0u;
  __syncthreads();
  for (int i = t; i < cnt; i += 256) {
    float v = keyval((unsigned int)(sc[i] >> 32));
    atomicAdd(&hist[binof(v)], 1u);
  }
  __syncthreads();

  // suffix counts
  unsigned int csum = 0;
  #pragma unroll
  for (int j = 0; j < 8; j++) csum += hist[t * 8 + j];
  sS[t] = csum;
  __syncthreads();
  for (int off = 1; off < 256; off <<= 1) {
    unsigned int v2 = (t + off < 256) ? sS[t + off] : 0u;
    __syncthreads();
    sS[t] += v2;
    __syncthreads();
  }
  {
    unsigned int above = (t < 255) ? sS[t + 1] : 0u;
    unsigned int run = 0;
    for (int j = 7; j >= 0; j--) {
      int bb = t * 8 + j;
      unsigned int S = above + run, h = hist[bb];
      if (h) {
        if (S < 32u  && 32u  <= S + h) { s_bb[0] = bb; s_bc[0] = S; }
        if (S < 128u && 128u <= S + h) { s_bb[1] = bb; s_bc[1] = S; }
        if (S < 256u && 256u <= S + h) { s_bb[2] = bb; s_bc[2] = S; }
      }
      run += h;
    }
  }
  __syncthreads();

  // resolve exact threshold ukeys inside each boundary bin
  for (int ri = 0; ri < 3; ri++) {
    const int r = (ri == 0) ? 32 : (ri == 1) ? 128 : 256;
    int bb = s_bb[ri];
    int cA = (int)s_bc[ri];
    if (t == 0) s_scnt = 0;
    __syncthreads();
    for (int i = t; i < cnt; i += 256) {
      float v = keyval((unsigned int)(sc[i] >> 32));
      if (binof(v) == bb) {
        int p = atomicAdd(&s_scnt, 1);
        if (p < 256) scratch[p] = sc[i];
      }
    }
    __syncthreads();
    int m = min(s_scnt, 256);
    for (int i = t; i < m; i += 256) {
      u64 me = scratch[i];
      int rk = 0;
      for (int j2 = 0; j2 < m; j2++) rk += (scratch[j2] > me) ? 1 : 0;
      if (rk == r - cA - 1) s_T[ri] = me;
    }
    __syncthreads();
  }

  // classify candidates, collect winners into win[]
  if (t == 0) { s_pos = 0u; s_l0 = 0u; }
  __syncthreads();
  const u64 T32 = s_T[0], T128 = s_T[1], T256 = s_T[2];
  for (int i = t; i < cnt; i += 256) {
    u64 e = sc[i];
    int w = (e >= T32) ? 3 : (e >= T128) ? 2 : (e >= T256) ? 1 : 0;
    if (w) {
      unsigned int p = atomicAdd(&s_pos, 1u);
      int idx = (int)(~(unsigned int)e) & (L_DIM - 1);
      float v = keyval((unsigned int)(e >> 32));
      float rv = fmaxf(v, 0.f);
      if (p < 256u)
        win[p] = make_uint2((unsigned int)idx | ((unsigned int)w << 20), __float_as_uint(rv));
      if (rv > 0.f) atomicAdd(&s_l0, 1u);
    }
  }
  __syncthreads();
  // pad (sorts last; weight bits decode to 0 -> scatter writes 0, harmless)
  for (int i = (int)s_pos + t; i < 256; i += 256) win[i] = make_uint2(0xFFFFFu, 0u);
  __syncthreads();

  // bitonic sort win[] ascending by latent idx
  for (int k = 2; k <= 256; k <<= 1) {
    for (int j = k >> 1; j > 0; j >>= 1) {
      int x = t ^ j;
      if (x > t) {
        uint2 a = win[t], bb2 = win[x];
        bool asc = ((t & k) == 0);
        bool swap = asc ? ((a.x & 0xFFFFFu) > (bb2.x & 0xFFFFFu))
                        : ((a.x & 0xFFFFFu) < (bb2.x & 0xFFFFFu));
        if (swap) { win[t] = bb2; win[x] = a; }
      }
      __syncthreads();
    }
  }

  lists[(size_t)b * 256 + t] = win[t];

  // scatter winners over the (already drained) zeroed row: one 4B store per thread
  {
    uint2 e = win[t];
    int idx = (int)(e.x & 0xFFFFFu) & (L_DIM - 1);
    unsigned int wg = (e.x >> 20) & 3u;
    float rv = __uint_as_float(e.y);
    rowp[idx] = rv * (float)wg * (1.f / 3.f);
  }

  if (t == 0) atomicAdd(l0p, s_l0);
}

// ---------------- sparse decode: int8 W_dec gather, 512 thr, 4 groups ----------------
// r6-proven structure (depth-8): 8 independent gathers in flight + scalar row base via
// readfirstlane. Depth-16 (r7) regressed: VGPR >100 dropped occupancy 32->20 waves/CU,
// which outweighed added per-wave depth for this latency-bound gather. Keep depth 8.
#define DEC_PROC(E, Q)                                             \
  do {                                                             \
    int wgt_ = (int)(((E).x >> 20) & 3u);                          \
    float v_ = __uint_as_float((E).y) * (1.0f / W8SCALE);          \
    float f_[8];                                                   \
    _Pragma("unroll")                                              \
    for (int j_ = 0; j_ < 4; j_++) {                               \
      f_[j_]     = (float)((int)((Q).x << (24 - 8 * j_)) >> 24);   \
      f_[4 + j_] = (float)((int)((Q).y << (24 - 8 * j_)) >> 24);   \
    }                                                              \
    if (wgt_ == 3) {                                               \
      _Pragma("unroll")                                            \
      for (int j_ = 0; j_ < 8; j_++) a1[j_] += v_ * f_[j_];        \
    } else if (wgt_ == 2) {                                        \
      _Pragma("unroll")                                            \
      for (int j_ = 0; j_ < 8; j_++) a2[j_] += v_ * f_[j_];        \
    } else {                                                       \
      _Pragma("unroll")                                            \
      for (int j_ = 0; j_ < 8; j_++) a3[j_] += v_ * f_[j_];        \
    }                                                              \
  } while (0)

__global__ __launch_bounds__(512) void k_decode(
    const uint2* __restrict__ lists, const unsigned char* __restrict__ W8,
    const unsigned short* __restrict__ skipb, const float* __restrict__ mlp,
    float* __restrict__ mdec, float* __restrict__ loss_acc) {
  __shared__ uint2 ll[256];
  __shared__ float part[3][24][128];   // [group-1][class*8+col][lane] - stride-1 in lane
  __shared__ float red[2];
  const int b = blockIdx.x, t = threadIdx.x;
  if (t < 256) ll[t] = lists[(size_t)b * 256 + t];
  __syncthreads();

  const int lane = t & 127, grp = t >> 7;   // 4 groups x 128 lanes
  const int c = lane * 8;                   // loop-invariant voffset (bytes)

  float a1[8] = {}, a2[8] = {}, a3[8] = {};

  // group grp processes sorted entries 4i+grp; batches of 8 independent gathers
  for (int i0 = 0; i0 < 64; i0 += 8) {
    uint2 e0 = ll[4 * (i0 + 0) + grp];
    uint2 e1 = ll[4 * (i0 + 1) + grp];
    uint2 e2 = ll[4 * (i0 + 2) + grp];
    uint2 e3 = ll[4 * (i0 + 3) + grp];
    uint2 e4 = ll[4 * (i0 + 4) + grp];
    uint2 e5 = ll[4 * (i0 + 5) + grp];
    uint2 e6 = ll[4 * (i0 + 6) + grp];
    uint2 e7 = ll[4 * (i0 + 7) + grp];
    // scalar row bases (entry index is uniform across the group's waves)
    const unsigned char* r0p = W8 + (size_t)((unsigned)__builtin_amdgcn_readfirstlane(e0.x) & (L_DIM - 1)) * D_IN;
    const unsigned char* r1p = W8 + (size_t)((unsigned)__builtin_amdgcn_readfirstlane(e1.x) & (L_DIM - 1)) * D_IN;
    const unsigned char* r2p = W8 + (size_t)((unsigned)__builtin_amdgcn_readfirstlane(e2.x) & (L_DIM - 1)) * D_IN;
    const unsigned char* r3p = W8 + (size_t)((unsigned)__builtin_amdgcn_readfirstlane(e3.x) & (L_DIM - 1)) * D_IN;
    const unsigned char* r4p = W8 + (size_t)((unsigned)__builtin_amdgcn_readfirstlane(e4.x) & (L_DIM - 1)) * D_IN;
    const unsigned char* r5p = W8 + (size_t)((unsigned)__builtin_amdgcn_readfirstlane(e5.x) & (L_DIM - 1)) * D_IN;
    const unsigned char* r6p = W8 + (size_t)((unsigned)__builtin_amdgcn_readfirstlane(e6.x) & (L_DIM - 1)) * D_IN;
    const unsigned char* r7p = W8 + (size_t)((unsigned)__builtin_amdgcn_readfirstlane(e7.x) & (L_DIM - 1)) * D_IN;
    // 8 independent gathers in flight
    uint2 q0 = *(const uint2*)(r0p + c);
    uint2 q1 = *(const uint2*)(r1p + c);
    uint2 q2 = *(const uint2*)(r2p + c);
    uint2 q3 = *(const uint2*)(r3p + c);
    uint2 q4 = *(const uint2*)(r4p + c);
    uint2 q5 = *(const uint2*)(r5p + c);
    uint2 q6 = *(const uint2*)(r6p + c);
    uint2 q7 = *(const uint2*)(r7p + c);
    DEC_PROC(e0, q0);
    DEC_PROC(e1, q1);
    DEC_PROC(e2, q2);
    DEC_PROC(e3, q3);
    DEC_PROC(e4, q4);
    DEC_PROC(e5, q5);
    DEC_PROC(e6, q6);
    DEC_PROC(e7, q7);
  }

  if (grp != 0) {
    #pragma unroll
    for (int j = 0; j < 8; j++) {
      part[grp - 1][j][lane]      = a1[j];
      part[grp - 1][8 + j][lane]  = a2[j];
      part[grp - 1][16 + j][lane] = a3[j];
    }
  }
  __syncthreads();

  float lsum = 0.f;
  if (grp == 0) {
    #pragma unroll
    for (int g = 0; g < 3; g++) {
      #pragma unroll
      for (int j = 0; j < 8; j++) {
        a1[j] += part[g][j][lane];
        a2[j] += part[g][8 + j][lane];
        a3[j] += part[g][16 + j][lane];
      }
    }
    u16x8 skv = *(const u16x8*)&skipb[(size_t)b * D_IN + c];
    f32x4 m0 = *(const f32x4*)&mlp[(size_t)b * D_IN + c];
    f32x4 m1 = *(const f32x4*)&mlp[(size_t)b * D_IN + c + 4];
    float mm[8] = {m0[0], m0[1], m0[2], m0[3], m1[0], m1[1], m1[2], m1[3]};
    float md[8];
    #pragma unroll
    for (int j = 0; j < 8; j++) {
      float sk   = bf2f(skv[j]);
      float d32  = sk + a1[j];
      float d128 = d32 + a2[j];
      float d256 = d128 + a3[j];
      md[j] = (d32 + d128 + d256) * (1.f / 3.f);
      float e1 = mm[j] - d32, e2 = mm[j] - d128, e3 = mm[j] - d256;
      lsum += e1 * e1 + e2 * e2 + e3 * e3;
    }
    f32x4 o0 = {md[0], md[1], md[2], md[3]};
    f32x4 o1 = {md[4], md[5], md[6], md[7]};
    *(f32x4*)&mdec[(size_t)b * D_IN + c]     = o0;
    *(f32x4*)&mdec[(size_t)b * D_IN + c + 4] = o1;
  }

  lsum = waveSum(lsum);                 // waves 2..7 sum to 0
  if ((t & 63) == 0 && t < 128) red[t >> 6] = lsum;
  __syncthreads();
  if (t == 0) atomicAdd(loss_acc, red[0] + red[1]);
}

// ---------------- finalize scalars ----------------
__global__ void k_final(const float* scal, const unsigned int* l0p, float* outscal) {
  outscal[0] = scal[0] / scal[1];
  outscal[1] = (float)(*l0p);
}

// ---------------- host launch ----------------
extern "C" void kernel_launch(void* const* d_in, const int* in_sizes, int n_in,
                              void* d_out, int out_size, void* d_ws, size_t ws_size,
                              hipStream_t stream) {
  (void)in_sizes; (void)n_in; (void)out_size; (void)ws_size;
  const float* x     = (const float*)d_in[0];
  const float* mlp   = (const float*)d_in[1];
  const float* Wenc  = (const float*)d_in[2];
  const float* benc  = (const float*)d_in[3];
  const float* Wdec  = (const float*)d_in[4];
  const float* bdec  = (const float*)d_in[5];
  const float* Wskip = (const float*)d_in[6];

  char* ws = (char*)d_ws;
  float*          scal    = (float*)(ws + 0);                 // [0]=loss [1]=var
  unsigned int*   l0p     = (unsigned int*)(ws + 8);
  float*          colsum  = (float*)(ws + 256);
  float*          colsq   = (float*)(ws + 4352);
  unsigned int*   rowcnt  = (unsigned int*)(ws + 8448);        // 16 KB
  unsigned short* xb      = (unsigned short*)(ws + 24832);     // 8 MB (bf16, for skip GEMM)
  unsigned char*  wenc8   = (unsigned char*)(ws + 8413440);    // 16 MB (fp8 W_enc, identity)
  unsigned char*  xf8     = (unsigned char*)(ws + 8413440 + 16777216);  // 4 MB (fp8 x, identity)
  unsigned short* wsktb   = (unsigned short*)(ws + 41967872);  // 2 MB
  unsigned short* skipb   = (unsigned short*)(ws + 44065024);  // 8 MB (bf16)
  uint2*          lists   = (uint2*)(ws + 52453632);           // 8 MB
  u64*            cand    = (u64*)(ws + 60842240);             // 32 MB
  unsigned char*  wdec8   = (unsigned char*)(ws + 60842240);   // 16 MB, aliases cand (after select)

  float* out  = (float*)d_out;
  float* menc = out;
  float* mdec = out + (size_t)B_ROWS * L_DIM;
  float* oscl = out + (size_t)B_ROWS * L_DIM + (size_t)B_ROWS * D_IN;

  k_prep<<<2048, 256, 0, stream>>>(x, xb, xf8, scal, colsum, colsq, rowcnt, (B_ROWS * D_IN) / 4);
  k_convert_fp8<<<2048, 256, 0, stream>>>(Wenc, wenc8, (L_DIM * D_IN) / 4);
  k_transpose_bf<<<dim3(32, 32), dim3(32, 32), 0, stream>>>(Wskip, wsktb, D_IN);
  k_var1<<<128, 256, 0, stream>>>(x, colsum, colsq);
  k_var2<<<1, 256, 0, stream>>>(colsum, colsq, scal);
  k_gemm_enc<<<dim3(L_DIM / 128, B_ROWS / 128), 256, 0, stream>>>(
      xf8, wenc8, benc, cand, rowcnt, B_ROWS, L_DIM, D_IN);
  k_gemm_skip<<<dim3(D_IN / 128, B_ROWS / 128), 256, 0, stream>>>(
      xb, wsktb, bdec, skipb, B_ROWS, D_IN, D_IN);
  k_select<<<B_ROWS, 256, 0, stream>>>(cand, rowcnt, xf8, wenc8, benc, menc, lists, l0p);
  k_convert_i8<<<2048, 256, 0, stream>>>(Wdec, (unsigned int*)wdec8, (L_DIM * D_IN) / 4);  // aliases cand
  k_decode<<<B_ROWS, 512, 0, stream>>>(lists, wdec8, skipb, mlp, mdec, scal);
  k_final<<<1, 1, 0, stream>>>(scal, l0p, oscl);
}